// Round 2
// baseline (263.325 us; speedup 1.0000x reference)
//
#include <hip/hip_runtime.h>
#include <hip/hip_cooperative_groups.h>
#include <hip/hip_bf16.h>
#include <math.h>

#define NN 2048      // nodes
#define NE 4096      // edges
#define D 128
#define NODE_K 1024
#define EDGE_K 2048
#define CAP 64       // per-node incident-edge list capacity (mean degree 4)
#define GRID 256
#define BLK 512

typedef const __hip_bfloat16* bfp;
typedef unsigned short u16;
typedef __attribute__((ext_vector_type(8))) short short8;     // 8 bf16 (4 VGPRs)
typedef __attribute__((ext_vector_type(4))) float floatx4;    // MFMA acc

#define MFMA16(a, b, c) __builtin_amdgcn_mfma_f32_16x16x32_bf16(a, b, c, 0, 0, 0)

__device__ __forceinline__ float b2f(__hip_bfloat16 x) { return __bfloat162float(x); }

// dual-path loads: f=1 -> fp32 input, f=0 -> bf16 input (bf16->fp32 is exact)
__device__ __forceinline__ float ldx(const void* p, size_t i, int f) {
  return f ? ((const float*)p)[i] : b2f(((bfp)p)[i]);
}
__device__ __forceinline__ float4 ldx4(const void* p, size_t i4, int f) {
  if (f) return ((const float4*)p)[i4];
  ushort4 u = ((const ushort4*)p)[i4];
  float4 r;
  r.x = __uint_as_float(((unsigned)u.x) << 16);
  r.y = __uint_as_float(((unsigned)u.y) << 16);
  r.z = __uint_as_float(((unsigned)u.z) << 16);
  r.w = __uint_as_float(((unsigned)u.w) << 16);
  return r;
}

// RNE fp32 -> (bf16 hi, bf16 lo): x ~= hi + lo, dropped part ~2^-17 |x|
__device__ __forceinline__ void split2(float x, u16& hi, u16& lo) {
  unsigned u = __float_as_uint(x);
  unsigned h = (u + 0x7FFFu + ((u >> 16) & 1u)) >> 16;
  hi = (u16)h;
  float r = x - __uint_as_float(h << 16);
  unsigned v = __float_as_uint(r);
  lo = (u16)((v + 0x7FFFu + ((v >> 16) & 1u)) >> 16);
}
__device__ __forceinline__ void build_frags(const float* v8, short8& fh, short8& fl) {
  #pragma unroll
  for (int i = 0; i < 8; ++i) {
    u16 h, l;
    split2(v8[i], h, l);
    fh[i] = (short)h; fl[i] = (short)l;
  }
}

// per-block dtype detect from first 1024 halves of node_features (2 KB, L2-hot)
__device__ __forceinline__ int detect_f(const u16* raw, int* s8) {
  int t = threadIdx.x;
  int weird = 0;
  for (int i = t; i < 1024; i += BLK) {
    unsigned int bits = ((unsigned int)raw[i]) << 16;
    float x = __uint_as_float(bits);
    float ax = fabsf(x);
    if (!(ax <= 1e3f) || (x != 0.f && ax < 1e-12f)) weird++;  // nan/inf/huge/denorm
  }
  #pragma unroll
  for (int m = 32; m >= 1; m >>= 1) weird += __shfl_xor(weird, m);
  if ((t & 63) == 0) s8[t >> 6] = weird;
  __syncthreads();
  int tot = 0;
  #pragma unroll
  for (int i = 0; i < BLK / 64; ++i) tot += s8[i];
  return (tot > 50) ? 1 : 0;  // 1 => inputs are fp32
}

struct FusedArgs {
  const void *nf, *ef, *wrn, *wre;
  const void* w[7];              // we, wn, wq, wk, wv, wo, w1 (each 128x128)
  const void *b1, *w2, *b2;
  const int *src, *dst;
  float *ns, *es;
  int *node_mask, *edge_topk, *deg, *lists;
  u16 *wtHi, *wtLo;              // [7][128 n][128 k] (transposed + split)
  u16 *feHi, *feLo;              // [NN*D | NE*D] row-major feature splits
  float *qkv;
  void *out;
};

// One cooperative kernel, 256 blocks x 512 thr (1 block/CU co-resident).
// Stages: A scores+prep | B ranks+lists | C h->qkv MFMA | D attention | E MLP.
// grid.sync between A-B-C-D; D->E is intra-block (ao stays in LDS).
__global__ __launch_bounds__(BLK, 2) void fused_kernel(FusedArgs a) {
  namespace cg = cooperative_groups;
  cg::grid_group grid = cg::this_grid();
  __shared__ int s8[BLK / 64];
  __shared__ __align__(16) float hf[8 * 64 * 4];    // frag-order h / o (8 KB)
  __shared__ __align__(16) float ao_lds[16 * 132];  // attn out, padded rows
  __shared__ __align__(16) float xl[16 * 132];      // gelu(x), padded
  __shared__ __align__(16) float w2t[16 * 132];     // w2 transposed, padded

  int b = blockIdx.x, t = threadIdx.x;
  int wave = t >> 6, lane = t & 63;
  int gid = b * BLK + t;          // 0..131071
  int gw = b * 8 + wave;          // 0..2047
  int f = detect_f((const u16*)a.nf, s8);

  // ================= stage A: scores (fp64) + splits + deg zero =================
  for (int wid = gw; wid < NN + NE; wid += 2048) {   // 3 rows per wave
    const void* base; const void* w; float* out; size_t r0;
    if (wid < NN) { base = a.nf; r0 = (size_t)wid * D; w = a.wrn; out = a.ns + wid; }
    else { int r = wid - NN; base = a.ef; r0 = (size_t)r * D; w = a.wre; out = a.es + r; }
    double p = (double)ldx(base, r0 + lane, f) * (double)ldx(w, lane, f)
             + (double)ldx(base, r0 + lane + 64, f) * (double)ldx(w, lane + 64, f);
    #pragma unroll
    for (int m = 32; m >= 1; m >>= 1) p += __shfl_xor(p, m);
    if (lane == 0) *out = (float)p;
  }
  if (gid < 28672) {  // weight split+transpose, coalesced ushort4: Wt[n][k0..k0+3]
    int tau = gid;
    int w = tau >> 12, rem = tau & 4095;
    int n = rem >> 5, k0 = (rem & 31) * 4;
    ushort4 hi, lo;
    split2(ldx(a.w[w], (size_t)(k0 + 0) * 128 + n, f), hi.x, lo.x);
    split2(ldx(a.w[w], (size_t)(k0 + 1) * 128 + n, f), hi.y, lo.y);
    split2(ldx(a.w[w], (size_t)(k0 + 2) * 128 + n, f), hi.z, lo.z);
    split2(ldx(a.w[w], (size_t)(k0 + 3) * 128 + n, f), hi.w, lo.w);
    ((ushort4*)a.wtHi)[tau] = hi;
    ((ushort4*)a.wtLo)[tau] = lo;
  }
  for (int g4 = gid; g4 < (NN + NE) * D / 4; g4 += GRID * BLK) {  // feature split
    float4 x = (g4 < NN * D / 4) ? ldx4(a.nf, g4, f)
                                 : ldx4(a.ef, g4 - NN * D / 4, f);
    ushort4 hi, lo;
    split2(x.x, hi.x, lo.x);
    split2(x.y, hi.y, lo.y);
    split2(x.z, hi.z, lo.z);
    split2(x.w, hi.w, lo.w);
    ((ushort4*)a.feHi)[g4] = hi;
    ((ushort4*)a.feLo)[g4] = lo;
  }
  if (gid < NN) a.deg[gid] = 0;
  grid.sync();

  // ================= stage B: exact top-k ranks + incident lists =================
  {
    // node rank: wave gw handles node gw (stable ties == lax.top_k)
    float si = a.ns[gw];
    int rank = 0;
    for (int j4 = lane; j4 < NN / 4; j4 += 64) {
      float4 sj = ((const float4*)a.ns)[j4];
      int j = j4 * 4;
      rank += (sj.x > si) || (sj.x == si && j + 0 < gw);
      rank += (sj.y > si) || (sj.y == si && j + 1 < gw);
      rank += (sj.z > si) || (sj.z == si && j + 2 < gw);
      rank += (sj.w > si) || (sj.w == si && j + 3 < gw);
    }
    #pragma unroll
    for (int m = 32; m >= 1; m >>= 1) rank += __shfl_xor(rank, m);
    if (lane == 0) a.node_mask[gw] = (rank < NODE_K) ? 1 : 0;
    #pragma unroll
    for (int rr = 0; rr < 2; ++rr) {  // edge ranks gw, gw+2048
      int i = gw + rr * 2048;
      float se = a.es[i];
      int rk = 0;
      for (int j4 = lane; j4 < NE / 4; j4 += 64) {
        float4 sj = ((const float4*)a.es)[j4];
        int j = j4 * 4;
        rk += (sj.x > se) || (sj.x == se && j + 0 < i);
        rk += (sj.y > se) || (sj.y == se && j + 1 < i);
        rk += (sj.z > se) || (sj.z == se && j + 2 < i);
        rk += (sj.w > se) || (sj.w == se && j + 3 < i);
      }
      #pragma unroll
      for (int m = 32; m >= 1; m >>= 1) rk += __shfl_xor(rk, m);
      if (lane == 0) a.edge_topk[i] = (rk < EDGE_K) ? 1 : 0;
    }
    if (gid < NE) {  // incident lists
      int e = gid;
      int sn = a.src[e], dn = a.dst[e];
      int p = atomicAdd(&a.deg[sn], 1);
      if (p >= 0 && p < CAP) a.lists[sn * CAP + p] = e;
      if (dn != sn) {
        p = atomicAdd(&a.deg[dn], 1);
        if (p >= 0 && p < CAP) a.lists[dn * CAP + p] = e;
      }
    }
  }
  grid.sync();

  // ========= stage C: MFMA h = efm@WE + (nfs+nfd)@WN; q,k,v = h@WQ/WK/WV =========
  int row0 = b * 16;
  {
    int qd = lane >> 4, c = lane & 15;
    int e = row0 + c;                 // A-row this lane gathers (m = c)
    int sn = a.src[e], dn = a.dst[e];
    bool em = a.edge_topk[e] && a.node_mask[sn] && a.node_mask[dn];
    int n0 = wave * 16;
    const u16* efH = a.feHi + (size_t)NN * D;
    const u16* efL = a.feLo + (size_t)NN * D;
    const short8 z8 = {0, 0, 0, 0, 0, 0, 0, 0};

    short8 A1h[4], A1l[4], Sh[4], Sl[4], Dh[4], Dl[4];
    short8 BEh[4], BEl[4], BNh[4], BNl[4];
    #pragma unroll
    for (int ks = 0; ks < 4; ++ks) {
      int k0 = ks * 32 + qd * 8;
      A1h[ks] = *(const short8*)(efH + (size_t)e * D + k0);
      A1l[ks] = *(const short8*)(efL + (size_t)e * D + k0);
      Sh[ks]  = *(const short8*)(a.feHi + (size_t)sn * D + k0);
      Sl[ks]  = *(const short8*)(a.feLo + (size_t)sn * D + k0);
      Dh[ks]  = *(const short8*)(a.feHi + (size_t)dn * D + k0);
      Dl[ks]  = *(const short8*)(a.feLo + (size_t)dn * D + k0);
      size_t bo = (size_t)(n0 + c) * 128 + k0;
      BEh[ks] = *(const short8*)(a.wtHi + bo);
      BEl[ks] = *(const short8*)(a.wtLo + bo);
      BNh[ks] = *(const short8*)(a.wtHi + 16384 + bo);
      BNl[ks] = *(const short8*)(a.wtLo + 16384 + bo);
    }
    if (!em) {
      #pragma unroll
      for (int ks = 0; ks < 4; ++ks) { A1h[ks] = z8; A1l[ks] = z8; }
    }
    floatx4 accE = {0.f, 0.f, 0.f, 0.f};
    floatx4 accN = {0.f, 0.f, 0.f, 0.f};
    #pragma unroll
    for (int ks = 0; ks < 4; ++ks) {
      accE = MFMA16(A1h[ks], BEh[ks], accE);
      accN = MFMA16(Sh[ks], BNh[ks], accN);
      accE = MFMA16(A1l[ks], BEh[ks], accE);
      accN = MFMA16(Sl[ks], BNh[ks], accN);
      accE = MFMA16(A1h[ks], BEl[ks], accE);
      accN = MFMA16(Sh[ks], BNl[ks], accN);
      accN = MFMA16(Dh[ks], BNh[ks], accN);
      accN = MFMA16(Dl[ks], BNh[ks], accN);
      accN = MFMA16(Dh[ks], BNl[ks], accN);
    }
    {
      int np = n0 + c;
      int kd = np >> 5, qq = (np >> 3) & 3, half = (c >> 2) & 1, j4 = c & 3;
      #pragma unroll
      for (int r = 0; r < 4; ++r)
        hf[((kd * 2 + half) * 64 + qq * 16 + 4 * qd + r) * 4 + j4] = accE[r] + accN[r];
    }
    short8 BQh[4], BQl[4], BKh[4], BKl[4], BVh[4], BVl[4];
    #pragma unroll
    for (int ks = 0; ks < 4; ++ks) {
      size_t bo = (size_t)(n0 + c) * 128 + ks * 32 + qd * 8;
      BQh[ks] = *(const short8*)(a.wtHi + 2 * 16384 + bo);
      BQl[ks] = *(const short8*)(a.wtLo + 2 * 16384 + bo);
      BKh[ks] = *(const short8*)(a.wtHi + 3 * 16384 + bo);
      BKl[ks] = *(const short8*)(a.wtLo + 3 * 16384 + bo);
      BVh[ks] = *(const short8*)(a.wtHi + 4 * 16384 + bo);
      BVl[ks] = *(const short8*)(a.wtLo + 4 * 16384 + bo);
    }
    __syncthreads();
    floatx4 aq = {0.f, 0.f, 0.f, 0.f};
    floatx4 ak = {0.f, 0.f, 0.f, 0.f};
    floatx4 av = {0.f, 0.f, 0.f, 0.f};
    #pragma unroll
    for (int ks = 0; ks < 4; ++ks) {
      float4 p0 = *(const float4*)&hf[((ks * 2 + 0) * 64 + lane) * 4];
      float4 p1 = *(const float4*)&hf[((ks * 2 + 1) * 64 + lane) * 4];
      float v8[8] = {p0.x, p0.y, p0.z, p0.w, p1.x, p1.y, p1.z, p1.w};
      short8 ah, al;
      build_frags(v8, ah, al);
      aq = MFMA16(ah, BQh[ks], aq);
      ak = MFMA16(ah, BKh[ks], ak);
      av = MFMA16(ah, BVh[ks], av);
      aq = MFMA16(al, BQh[ks], aq);
      ak = MFMA16(al, BKh[ks], ak);
      av = MFMA16(al, BVh[ks], av);
      aq = MFMA16(ah, BQl[ks], aq);
      ak = MFMA16(ah, BKl[ks], ak);
      av = MFMA16(ah, BVl[ks], av);
    }
    #pragma unroll
    for (int r = 0; r < 4; ++r) {
      size_t ro = (size_t)(row0 + 4 * qd + r) * D + n0 + c;
      a.qkv[ro] = aq[r];
      a.qkv[(size_t)NE * D + ro] = ak[r];
      a.qkv[(size_t)2 * NE * D + ro] = av[r];
    }
  }
  grid.sync();

  // ====== stage D: sparse attention, half-wave (32 lanes) per edge, 4 dims/lane ======
  // lane l5 holds dims j = l5 + 32h, h = head 0..3; head reductions are 32-lane shfls.
  {
    const float* qb = a.qkv;
    const float* kb = a.qkv + (size_t)NE * D;
    const float* vb = a.qkv + (size_t)2 * NE * D;
    int half = lane >> 5, l5 = lane & 31;
    int el = wave * 2 + half;         // 0..15
    int e = row0 + el;
    int sn = a.src[e], dn = a.dst[e];
    const float scale = 0.17677669529663687f;  // 1/sqrt(32)
    float q4[4], m[4], lsum[4], acc[4];
    #pragma unroll
    for (int h = 0; h < 4; ++h) {
      q4[h] = qb[(size_t)e * D + l5 + 32 * h];
      m[h] = -1e30f; lsum[h] = 0.f; acc[h] = 0.f;
    }
    int degA = max(0, min(a.deg[sn], CAP));
    for (int i = 0; i < degA; ++i) {
      int fe = a.lists[sn * CAP + i];
      float p[4], vv[4];
      #pragma unroll
      for (int h = 0; h < 4; ++h) {
        p[h]  = q4[h] * kb[(size_t)fe * D + l5 + 32 * h];
        vv[h] = vb[(size_t)fe * D + l5 + 32 * h];
      }
      #pragma unroll
      for (int mk = 16; mk >= 1; mk >>= 1) {
        #pragma unroll
        for (int h = 0; h < 4; ++h) p[h] += __shfl_xor(p[h], mk);
      }
      #pragma unroll
      for (int h = 0; h < 4; ++h) {
        float s = p[h] * scale;
        float mn = fmaxf(m[h], s);
        float corr = expf(m[h] - mn);
        float w = expf(s - mn);
        lsum[h] = lsum[h] * corr + w;
        acc[h] = acc[h] * corr + w * vv[h];
        m[h] = mn;
      }
    }
    if (dn != sn) {
      int degB = max(0, min(a.deg[dn], CAP));
      for (int i = 0; i < degB; ++i) {
        int fe = a.lists[dn * CAP + i];
        if (a.src[fe] == sn || a.dst[fe] == sn) continue;  // already in list A
        float p[4], vv[4];
        #pragma unroll
        for (int h = 0; h < 4; ++h) {
          p[h]  = q4[h] * kb[(size_t)fe * D + l5 + 32 * h];
          vv[h] = vb[(size_t)fe * D + l5 + 32 * h];
        }
        #pragma unroll
        for (int mk = 16; mk >= 1; mk >>= 1) {
          #pragma unroll
          for (int h = 0; h < 4; ++h) p[h] += __shfl_xor(p[h], mk);
        }
        #pragma unroll
        for (int h = 0; h < 4; ++h) {
          float s = p[h] * scale;
          float mn = fmaxf(m[h], s);
          float corr = expf(m[h] - mn);
          float w = expf(s - mn);
          lsum[h] = lsum[h] * corr + w;
          acc[h] = acc[h] * corr + w * vv[h];
          m[h] = mn;
        }
      }
    }
    #pragma unroll
    for (int h = 0; h < 4; ++h)
      ao_lds[el * 132 + l5 + 32 * h] = acc[h] / fmaxf(lsum[h], 1e-37f);
  }
  __syncthreads();

  // ====== stage E: MFMA o = ao@WO; x = gelu(o@W1+b1); logits = x@W2+b2 ======
  {
    int qd = lane >> 4, c = lane & 15;
    int n0 = wave * 16;
    short8 BOh[4], BOl[4], B1h[4], B1l[4];
    #pragma unroll
    for (int ks = 0; ks < 4; ++ks) {
      size_t bo = (size_t)(n0 + c) * 128 + ks * 32 + qd * 8;
      BOh[ks] = *(const short8*)(a.wtHi + 5 * 16384 + bo);
      BOl[ks] = *(const short8*)(a.wtLo + 5 * 16384 + bo);
      B1h[ks] = *(const short8*)(a.wtHi + 6 * 16384 + bo);
      B1l[ks] = *(const short8*)(a.wtLo + 6 * 16384 + bo);
    }
    floatx4 acc = {0.f, 0.f, 0.f, 0.f};
    #pragma unroll
    for (int ks = 0; ks < 4; ++ks) {
      int k0 = ks * 32 + qd * 8;
      const float* ap = &ao_lds[c * 132 + k0];   // padded: 2-way banks, aligned
      float4 p0 = *(const float4*)ap;
      float4 p1 = *(const float4*)(ap + 4);
      float v8[8] = {p0.x, p0.y, p0.z, p0.w, p1.x, p1.y, p1.z, p1.w};
      short8 ah, al;
      build_frags(v8, ah, al);
      acc = MFMA16(ah, BOh[ks], acc);
      acc = MFMA16(al, BOh[ks], acc);
      acc = MFMA16(ah, BOl[ks], acc);
    }
    __syncthreads();   // hf was read in stage C epilogue; safe rewrite boundary
    {
      int np = n0 + c;
      int kd = np >> 5, qq = (np >> 3) & 3, half = (c >> 2) & 1, j4 = c & 3;
      #pragma unroll
      for (int r = 0; r < 4; ++r)
        hf[((kd * 2 + half) * 64 + qq * 16 + 4 * qd + r) * 4 + j4] = acc[r];
    }
    __syncthreads();
    floatx4 a2c = {0.f, 0.f, 0.f, 0.f};
    #pragma unroll
    for (int ks = 0; ks < 4; ++ks) {
      float4 p0 = *(const float4*)&hf[((ks * 2 + 0) * 64 + lane) * 4];
      float4 p1 = *(const float4*)&hf[((ks * 2 + 1) * 64 + lane) * 4];
      float v8[8] = {p0.x, p0.y, p0.z, p0.w, p1.x, p1.y, p1.z, p1.w};
      short8 ah, al;
      build_frags(v8, ah, al);
      a2c = MFMA16(ah, B1h[ks], a2c);
      a2c = MFMA16(al, B1h[ks], a2c);
      a2c = MFMA16(ah, B1l[ks], a2c);
    }
    float bj = ldx(a.b1, n0 + c, f);
    #pragma unroll
    for (int r = 0; r < 4; ++r) {
      float u = a2c[r] + bj;
      float inner = 0.7978845608028654f * (u + 0.044715f * u * u * u);
      xl[(4 * qd + r) * 132 + n0 + c] = 0.5f * u * (1.f + tanhf(inner));
    }
    for (int i = t; i < D * 16; i += BLK) {
      int kk = i >> 4, cc = i & 15;
      w2t[cc * 132 + kk] = ldx(a.w2, i, f);
    }
    __syncthreads();
    if (t < 256) {  // logits = x @ w2 + b2, float4 LDS dot
      int r = t >> 4, cc = t & 15;
      const float4* xr = (const float4*)&xl[r * 132];
      const float4* wr = (const float4*)&w2t[cc * 132];
      float s = 0.f;
      #pragma unroll
      for (int k4 = 0; k4 < D / 4; ++k4) {
        float4 xa = xr[k4], wb = wr[k4];
        s += xa.x * wb.x + xa.y * wb.y + xa.z * wb.z + xa.w * wb.w;
      }
      s += ldx(a.b2, cc, f);
      int idx = (row0 + r) * 16 + cc;
      if (f) ((float*)a.out)[idx] = s;
      else ((__hip_bfloat16*)a.out)[idx] = __float2bfloat16(s);
    }
  }
}

extern "C" void kernel_launch(void* const* d_in, const int* in_sizes, int n_in,
                              void* d_out, int out_size, void* d_ws, size_t ws_size,
                              hipStream_t stream) {
  const int* eidx = (const int*)d_in[2];

  size_t off = 0;
  char* base = (char*)d_ws;
  auto alloc = [&](size_t nbytes) -> void* {
    void* p = base + off;
    off += (nbytes + 255) & ~(size_t)255;
    return p;
  };
  float* ns      = (float*)alloc(NN * sizeof(float));
  float* es      = (float*)alloc(NE * sizeof(float));
  int* node_mask = (int*)alloc(NN * sizeof(int));
  int* edge_topk = (int*)alloc(NE * sizeof(int));
  int* deg       = (int*)alloc(NN * sizeof(int));
  int* lists     = (int*)alloc((size_t)NN * CAP * sizeof(int));
  u16* wtHi      = (u16*)alloc((size_t)7 * 16384 * sizeof(u16));
  u16* wtLo      = (u16*)alloc((size_t)7 * 16384 * sizeof(u16));
  u16* feHi      = (u16*)alloc((size_t)(NN + NE) * D * sizeof(u16));
  u16* feLo      = (u16*)alloc((size_t)(NN + NE) * D * sizeof(u16));
  float* qkv     = (float*)alloc((size_t)3 * NE * D * sizeof(float));

  FusedArgs fa;
  fa.nf = d_in[0]; fa.ef = d_in[1]; fa.wrn = d_in[3]; fa.wre = d_in[4];
  fa.w[0] = d_in[5];  fa.w[1] = d_in[6];  fa.w[2] = d_in[7];
  fa.w[3] = d_in[8];  fa.w[4] = d_in[9];  fa.w[5] = d_in[10]; fa.w[6] = d_in[11];
  fa.b1 = d_in[12]; fa.w2 = d_in[13]; fa.b2 = d_in[14];
  fa.src = eidx; fa.dst = eidx + NE;
  fa.ns = ns; fa.es = es;
  fa.node_mask = node_mask; fa.edge_topk = edge_topk;
  fa.deg = deg; fa.lists = lists;
  fa.wtHi = wtHi; fa.wtLo = wtLo; fa.feHi = feHi; fa.feLo = feLo;
  fa.qkv = qkv;
  fa.out = d_out;

  void* kargs[] = {(void*)&fa};
  hipLaunchCooperativeKernel(fused_kernel, dim3(GRID), dim3(BLK), kargs, 0, stream);
}

// Round 3
// 161.027 us; speedup vs baseline: 1.6353x; 1.6353x over previous
//
#include <hip/hip_runtime.h>
#include <hip/hip_bf16.h>
#include <math.h>

#define NN 2048      // nodes
#define NE 4096      // edges
#define D 128
#define NODE_K 1024
#define EDGE_K 2048
#define CAP 64       // per-node incident-edge list capacity (mean degree 4)

typedef const __hip_bfloat16* bfp;
typedef unsigned short u16;
typedef __attribute__((ext_vector_type(8))) short short8;     // 8 bf16 (4 VGPRs)
typedef __attribute__((ext_vector_type(4))) float floatx4;    // MFMA acc

#define MFMA16(a, b, c) __builtin_amdgcn_mfma_f32_16x16x32_bf16(a, b, c, 0, 0, 0)

__device__ __forceinline__ float b2f(__hip_bfloat16 x) { return __bfloat162float(x); }

// dual-path loads: f=1 -> fp32 input, f=0 -> bf16 input (bf16->fp32 is exact)
__device__ __forceinline__ float ldx(const void* p, size_t i, int f) {
  return f ? ((const float*)p)[i] : b2f(((bfp)p)[i]);
}
__device__ __forceinline__ float4 ldx4(const void* p, size_t i4, int f) {
  if (f) return ((const float4*)p)[i4];
  ushort4 u = ((const ushort4*)p)[i4];
  float4 r;
  r.x = __uint_as_float(((unsigned)u.x) << 16);
  r.y = __uint_as_float(((unsigned)u.y) << 16);
  r.z = __uint_as_float(((unsigned)u.z) << 16);
  r.w = __uint_as_float(((unsigned)u.w) << 16);
  return r;
}

// RNE fp32 -> (bf16 hi, bf16 lo): x ~= hi + lo, dropped part ~2^-17 |x|
__device__ __forceinline__ void split2(float x, u16& hi, u16& lo) {
  unsigned u = __float_as_uint(x);
  unsigned h = (u + 0x7FFFu + ((u >> 16) & 1u)) >> 16;
  hi = (u16)h;
  float r = x - __uint_as_float(h << 16);
  unsigned v = __float_as_uint(r);
  lo = (u16)((v + 0x7FFFu + ((v >> 16) & 1u)) >> 16);
}
__device__ __forceinline__ void build_frags(const float* v8, short8& fh, short8& fl) {
  #pragma unroll
  for (int i = 0; i < 8; ++i) {
    u16 h, l;
    split2(v8[i], h, l);
    fh[i] = (short)h; fl[i] = (short)l;
  }
}

// per-block dtype detect from first 1024 halves of node_features (2 KB, L2-hot)
template <int NT>
__device__ __forceinline__ int detect_f(const u16* raw, int* s8) {
  int t = threadIdx.x;
  int weird = 0;
  for (int i = t; i < 1024; i += NT) {
    unsigned int bits = ((unsigned int)raw[i]) << 16;
    float x = __uint_as_float(bits);
    float ax = fabsf(x);
    if (!(ax <= 1e3f) || (x != 0.f && ax < 1e-12f)) weird++;  // nan/inf/huge/denorm
  }
  #pragma unroll
  for (int m = 32; m >= 1; m >>= 1) weird += __shfl_xor(weird, m);
  if ((t & 63) == 0) s8[t >> 6] = weird;
  __syncthreads();
  int tot = 0;
  #pragma unroll
  for (int i = 0; i < NT / 64; ++i) tot += s8[i];
  return (tot > 50) ? 1 : 0;  // 1 => inputs are fp32
}

struct K1Args {
  const void *nf, *ef, *wrn, *wre;
  const void* w[7];              // we, wn, wq, wk, wv, wo, w1 (each 128x128)
  const int *src, *dst;
  float *ns, *es;
  int *deg, *lists, *flag;
  u16 *wtHi, *wtLo;              // [7][128 n][128 k] (transposed + split)
  u16 *feHi, *feLo;              // [NN*D | NE*D] row-major feature splits
};

// ---------- K1: scores (fp64) + splits + incident lists (LDS counters) ----------
#define SCORE_BLOCKS ((NN + NE) / 4)   // 1536
#define WPREP_BLOCKS 112               // 28672 ushort4-tasks / 256
#define FSPLIT_BLOCKS 192              // 196608 float4-tasks / (256*4)
#define K1_BLOCKS (SCORE_BLOCKS + WPREP_BLOCKS + FSPLIT_BLOCKS + 1)
__global__ __launch_bounds__(256) void scores_prep_lists_kernel(K1Args a) {
  __shared__ int s8[4];
  int b = blockIdx.x, t = threadIdx.x;
  int f = detect_f<256>((const u16*)a.nf, s8);
  if (b < SCORE_BLOCKS) {
    int wid = b * 4 + (t >> 6), lane = t & 63;
    const void* base; const void* w; float* out; size_t r0;
    if (wid < NN) { base = a.nf; r0 = (size_t)wid * D; w = a.wrn; out = a.ns + wid; }
    else { int r = wid - NN; base = a.ef; r0 = (size_t)r * D; w = a.wre; out = a.es + r; }
    double p = (double)ldx(base, r0 + lane, f) * (double)ldx(w, lane, f)
             + (double)ldx(base, r0 + lane + 64, f) * (double)ldx(w, lane + 64, f);
    #pragma unroll
    for (int m = 32; m >= 1; m >>= 1) p += __shfl_xor(p, m);
    if (lane == 0) *out = (float)p;
  } else if (b < SCORE_BLOCKS + WPREP_BLOCKS) {
    // weight split+transpose, coalesced ushort4 stores: Wt[n][k0..k0+3]
    int tau = (b - SCORE_BLOCKS) * 256 + t;  // 0..28671
    int w = tau >> 12, rem = tau & 4095;
    int n = rem >> 5, k0 = (rem & 31) * 4;
    ushort4 hi, lo;
    split2(ldx(a.w[w], (size_t)(k0 + 0) * 128 + n, f), hi.x, lo.x);
    split2(ldx(a.w[w], (size_t)(k0 + 1) * 128 + n, f), hi.y, lo.y);
    split2(ldx(a.w[w], (size_t)(k0 + 2) * 128 + n, f), hi.z, lo.z);
    split2(ldx(a.w[w], (size_t)(k0 + 3) * 128 + n, f), hi.w, lo.w);
    ((ushort4*)a.wtHi)[tau] = hi;
    ((ushort4*)a.wtLo)[tau] = lo;
  } else if (b < SCORE_BLOCKS + WPREP_BLOCKS + FSPLIT_BLOCKS) {
    // feature split: float4 in, 2x ushort4 out (NF then EF, row-major)
    int fb = b - SCORE_BLOCKS - WPREP_BLOCKS;  // 0..191
    #pragma unroll
    for (int i = 0; i < 4; ++i) {
      int g4 = fb * 1024 + i * 256 + t;        // 0..196607
      float4 x = (g4 < NN * D / 4) ? ldx4(a.nf, g4, f)
                                   : ldx4(a.ef, g4 - NN * D / 4, f);
      ushort4 hi, lo;
      split2(x.x, hi.x, lo.x);
      split2(x.y, hi.y, lo.y);
      split2(x.z, hi.z, lo.z);
      split2(x.w, hi.w, lo.w);
      ((ushort4*)a.feHi)[g4] = hi;
      ((ushort4*)a.feLo)[g4] = lo;
    }
  } else {
    // incident lists via LDS degree counters (one block owns all 4096 edges)
    __shared__ int ldeg[NN];
    for (int i = t; i < NN; i += 256) ldeg[i] = 0;
    __syncthreads();
    #pragma unroll
    for (int i = 0; i < NE / 256; ++i) {
      int e = i * 256 + t;
      int sn = a.src[e], dn = a.dst[e];
      int p = atomicAdd(&ldeg[sn], 1);
      if (p < CAP) a.lists[sn * CAP + p] = e;
      if (dn != sn) {
        p = atomicAdd(&ldeg[dn], 1);
        if (p < CAP) a.lists[dn * CAP + p] = e;
      }
    }
    __syncthreads();
    for (int i = t; i < NN; i += 256) a.deg[i] = ldeg[i];
    if (t == 0) a.flag[0] = f;
  }
}

// ---------- K2: MFMA h = efm@WE + (nfs+nfd)@WN; q,k,v = h@WQ/WK/WV ----------
// 512 thr (8 waves), 16 edge rows/block; wave w owns col-tile n0 = w*16.
// Top-k masks recomputed per block (48 rank scans over L2-hot scores, ~0.3us)
// -- cheaper than a dedicated kernel launch + gap.
__global__ __launch_bounds__(512) void h_qkv_mfma_kernel(
    const float* __restrict__ ns, const float* __restrict__ es,
    const u16* __restrict__ feHi, const u16* __restrict__ feLo,
    const int* __restrict__ src, const int* __restrict__ dst,
    const u16* __restrict__ wtHi, const u16* __restrict__ wtLo,
    float* __restrict__ qkv) {
  __shared__ __align__(16) float hf[8 * 64 * 4];  // frag-order h (fp32), 8 KB
  __shared__ int s_msk[3][16];                    // edge_topk, nm[src], nm[dst]
  int t = threadIdx.x;
  int wave = t >> 6, lane = t & 63;
  int qd = lane >> 4, c = lane & 15;
  int row0 = blockIdx.x * 16;

  // --- in-block top-k rank scans: 48 tasks = {edge, src-node, dst-node} x 16 ---
  for (int task = wave; task < 48; task += 8) {
    int kind = task >> 4, ti = task & 15;
    int e2 = row0 + ti;
    const float* arr; int len, K, tgt;
    if (kind == 0) { arr = es; len = NE; K = EDGE_K; tgt = e2; }
    else { arr = ns; len = NN; K = NODE_K; tgt = (kind == 1) ? src[e2] : dst[e2]; }
    float si = arr[tgt];
    int rank = 0;
    for (int j4 = lane; j4 < (len >> 2); j4 += 64) {
      float4 sj = ((const float4*)arr)[j4];
      int j = j4 * 4;
      rank += (sj.x > si) || (sj.x == si && j + 0 < tgt);
      rank += (sj.y > si) || (sj.y == si && j + 1 < tgt);
      rank += (sj.z > si) || (sj.z == si && j + 2 < tgt);
      rank += (sj.w > si) || (sj.w == si && j + 3 < tgt);
    }
    #pragma unroll
    for (int m = 32; m >= 1; m >>= 1) rank += __shfl_xor(rank, m);
    if (lane == 0) s_msk[kind][ti] = (rank < K) ? 1 : 0;
  }
  __syncthreads();

  int e = row0 + c;                 // A-row this lane gathers (m = c)
  int sn = src[e], dn = dst[e];
  bool em = s_msk[0][c] && s_msk[1][c] && s_msk[2][c];
  int n0 = wave * 16;
  const u16* efH = feHi + (size_t)NN * D;
  const u16* efL = feLo + (size_t)NN * D;
  const short8 z8 = {0, 0, 0, 0, 0, 0, 0, 0};

  // prefetch ALL h-pass A-operands (24 x 16B independent loads in flight)
  short8 A1h[4], A1l[4], Sh[4], Sl[4], Dh[4], Dl[4];
  short8 BEh[4], BEl[4], BNh[4], BNl[4];
  #pragma unroll
  for (int ks = 0; ks < 4; ++ks) {
    int k0 = ks * 32 + qd * 8;
    A1h[ks] = *(const short8*)(efH + (size_t)e * D + k0);
    A1l[ks] = *(const short8*)(efL + (size_t)e * D + k0);
    Sh[ks]  = *(const short8*)(feHi + (size_t)sn * D + k0);
    Sl[ks]  = *(const short8*)(feLo + (size_t)sn * D + k0);
    Dh[ks]  = *(const short8*)(feHi + (size_t)dn * D + k0);
    Dl[ks]  = *(const short8*)(feLo + (size_t)dn * D + k0);
    size_t bo = (size_t)(n0 + c) * 128 + k0;
    BEh[ks] = *(const short8*)(wtHi + bo);
    BEl[ks] = *(const short8*)(wtLo + bo);
    BNh[ks] = *(const short8*)(wtHi + 16384 + bo);
    BNl[ks] = *(const short8*)(wtLo + 16384 + bo);
  }
  if (!em) {
    #pragma unroll
    for (int ks = 0; ks < 4; ++ks) { A1h[ks] = z8; A1l[ks] = z8; }
  }
  floatx4 accE = {0.f, 0.f, 0.f, 0.f};
  floatx4 accN = {0.f, 0.f, 0.f, 0.f};
  #pragma unroll
  for (int ks = 0; ks < 4; ++ks) {
    accE = MFMA16(A1h[ks], BEh[ks], accE);
    accN = MFMA16(Sh[ks], BNh[ks], accN);
    accE = MFMA16(A1l[ks], BEh[ks], accE);
    accN = MFMA16(Sl[ks], BNh[ks], accN);
    accE = MFMA16(A1h[ks], BEl[ks], accE);
    accN = MFMA16(Sh[ks], BNl[ks], accN);
    accN = MFMA16(Dh[ks], BNh[ks], accN);
    accN = MFMA16(Dl[ks], BNh[ks], accN);
    accN = MFMA16(Dh[ks], BNl[ks], accN);
  }
  // write h (C-layout: row=4*qd+r, col=n0+c) into frag-order LDS
  {
    int np = n0 + c;
    int kd = np >> 5, qq = (np >> 3) & 3, half = (c >> 2) & 1, j4 = c & 3;
    #pragma unroll
    for (int r = 0; r < 4; ++r)
      hf[((kd * 2 + half) * 64 + qq * 16 + 4 * qd + r) * 4 + j4] = accE[r] + accN[r];
  }
  // prefetch q/k/v B-frags while h settles
  short8 BQh[4], BQl[4], BKh[4], BKl[4], BVh[4], BVl[4];
  #pragma unroll
  for (int ks = 0; ks < 4; ++ks) {
    size_t bo = (size_t)(n0 + c) * 128 + ks * 32 + qd * 8;
    BQh[ks] = *(const short8*)(wtHi + 2 * 16384 + bo);
    BQl[ks] = *(const short8*)(wtLo + 2 * 16384 + bo);
    BKh[ks] = *(const short8*)(wtHi + 3 * 16384 + bo);
    BKl[ks] = *(const short8*)(wtLo + 3 * 16384 + bo);
    BVh[ks] = *(const short8*)(wtHi + 4 * 16384 + bo);
    BVl[ks] = *(const short8*)(wtLo + 4 * 16384 + bo);
  }
  __syncthreads();
  // q,k,v: build h-frags ONCE per ks, feed 3 accumulator chains
  floatx4 aq = {0.f, 0.f, 0.f, 0.f};
  floatx4 ak = {0.f, 0.f, 0.f, 0.f};
  floatx4 av = {0.f, 0.f, 0.f, 0.f};
  #pragma unroll
  for (int ks = 0; ks < 4; ++ks) {
    float4 p0 = *(const float4*)&hf[((ks * 2 + 0) * 64 + lane) * 4];
    float4 p1 = *(const float4*)&hf[((ks * 2 + 1) * 64 + lane) * 4];
    float v8[8] = {p0.x, p0.y, p0.z, p0.w, p1.x, p1.y, p1.z, p1.w};
    short8 ah, al;
    build_frags(v8, ah, al);
    aq = MFMA16(ah, BQh[ks], aq);
    ak = MFMA16(ah, BKh[ks], ak);
    av = MFMA16(ah, BVh[ks], av);
    aq = MFMA16(al, BQh[ks], aq);
    ak = MFMA16(al, BKh[ks], ak);
    av = MFMA16(al, BVh[ks], av);
    aq = MFMA16(ah, BQl[ks], aq);
    ak = MFMA16(ah, BKl[ks], ak);
    av = MFMA16(ah, BVl[ks], av);
  }
  #pragma unroll
  for (int r = 0; r < 4; ++r) {
    size_t ro = (size_t)(row0 + 4 * qd + r) * D + n0 + c;
    qkv[ro] = aq[r];
    qkv[(size_t)NE * D + ro] = ak[r];
    qkv[(size_t)2 * NE * D + ro] = av[r];
  }
}

// ---------- K3: attention (wave/edge) + MFMA o@WO -> gelu MLP -> logits ----------
// 1024 thr = 16 waves; wave el owns edge row0+el (2 dims/lane: d and d+32).
// Attention output stays in LDS; MLP tile (16 edges) runs after syncthreads.
__global__ __launch_bounds__(1024) void attn_mlp_kernel(
    const float* __restrict__ qkv, const int* __restrict__ src,
    const int* __restrict__ dst, const int* __restrict__ deg,
    const int* __restrict__ lists,
    const u16* __restrict__ wtHi, const u16* __restrict__ wtLo,
    const void* __restrict__ b1, const void* __restrict__ w2,
    const void* __restrict__ b2, const int* __restrict__ flag,
    void* __restrict__ out) {
  __shared__ __align__(16) float ao_lds[16 * 132];  // attn out, padded rows
  __shared__ __align__(16) float hf[8 * 64 * 4];    // frag-order o (8 KB)
  __shared__ __align__(16) float xl[16 * 132];      // gelu(x), padded
  __shared__ __align__(16) float w2t[16 * 132];     // w2 transposed, padded
  int t = threadIdx.x;
  int wave = t >> 6, lane = t & 63;
  int row0 = blockIdx.x * 16;

  // ---------------- attention: wave el -> edge row0+el ----------------
  {
    const float* qb = qkv;
    const float* kb = qkv + (size_t)NE * D;
    const float* vb = qkv + (size_t)2 * NE * D;
    int half = lane >> 5, l5 = lane & 31;
    int d0 = l5 + 64 * half;          // head 2*half
    int d1 = d0 + 32;                 // head 2*half+1
    int e = row0 + wave;
    int sn = src[e], dn = dst[e];
    const float scale = 0.17677669529663687f;  // 1/sqrt(32)
    float q0 = qb[(size_t)e * D + d0], q1 = qb[(size_t)e * D + d1];
    float m0 = -1e30f, l0 = 0.f, a0 = 0.f;
    float m1 = -1e30f, l1 = 0.f, a1 = 0.f;
    int degA = max(0, min(deg[sn], CAP));
    for (int i = 0; i < degA; ++i) {
      int fe = lists[sn * CAP + i];
      float p0 = q0 * kb[(size_t)fe * D + d0];
      float p1 = q1 * kb[(size_t)fe * D + d1];
      #pragma unroll
      for (int mk = 16; mk >= 1; mk >>= 1) {
        p0 += __shfl_xor(p0, mk);
        p1 += __shfl_xor(p1, mk);
      }
      float v0 = vb[(size_t)fe * D + d0], v1 = vb[(size_t)fe * D + d1];
      float s0 = p0 * scale, s1 = p1 * scale;
      float n0_ = fmaxf(m0, s0), n1_ = fmaxf(m1, s1);
      float c0 = expf(m0 - n0_), c1 = expf(m1 - n1_);
      float w0 = expf(s0 - n0_), w1 = expf(s1 - n1_);
      l0 = l0 * c0 + w0; a0 = a0 * c0 + w0 * v0; m0 = n0_;
      l1 = l1 * c1 + w1; a1 = a1 * c1 + w1 * v1; m1 = n1_;
    }
    if (dn != sn) {
      int degB = max(0, min(deg[dn], CAP));
      for (int i = 0; i < degB; ++i) {
        int fe = lists[dn * CAP + i];
        if (src[fe] == sn || dst[fe] == sn) continue;  // already in list A
        float p0 = q0 * kb[(size_t)fe * D + d0];
        float p1 = q1 * kb[(size_t)fe * D + d1];
        #pragma unroll
        for (int mk = 16; mk >= 1; mk >>= 1) {
          p0 += __shfl_xor(p0, mk);
          p1 += __shfl_xor(p1, mk);
        }
        float v0 = vb[(size_t)fe * D + d0], v1 = vb[(size_t)fe * D + d1];
        float s0 = p0 * scale, s1 = p1 * scale;
        float n0_ = fmaxf(m0, s0), n1_ = fmaxf(m1, s1);
        float c0 = expf(m0 - n0_), c1 = expf(m1 - n1_);
        float w0 = expf(s0 - n0_), w1 = expf(s1 - n1_);
        l0 = l0 * c0 + w0; a0 = a0 * c0 + w0 * v0; m0 = n0_;
        l1 = l1 * c1 + w1; a1 = a1 * c1 + w1 * v1; m1 = n1_;
      }
    }
    ao_lds[wave * 132 + d0] = a0 / fmaxf(l0, 1e-37f);
    ao_lds[wave * 132 + d1] = a1 / fmaxf(l1, 1e-37f);
  }
  __syncthreads();

  // ---------------- MLP: waves 0-7 MFMA; waves 8-15 load w2t ----------------
  int f = flag[0];
  int qd = lane >> 4, c = lane & 15;
  int n0 = wave * 16;
  if (t < 512) {
    short8 BOh[4], BOl[4], B1h[4], B1l[4];
    #pragma unroll
    for (int ks = 0; ks < 4; ++ks) {
      size_t bo = (size_t)(n0 + c) * 128 + ks * 32 + qd * 8;
      BOh[ks] = *(const short8*)(wtHi + 5 * 16384 + bo);
      BOl[ks] = *(const short8*)(wtLo + 5 * 16384 + bo);
      B1h[ks] = *(const short8*)(wtHi + 6 * 16384 + bo);
      B1l[ks] = *(const short8*)(wtLo + 6 * 16384 + bo);
    }
    floatx4 acc = {0.f, 0.f, 0.f, 0.f};
    #pragma unroll
    for (int ks = 0; ks < 4; ++ks) {
      int k0 = ks * 32 + qd * 8;
      const float* ap = &ao_lds[c * 132 + k0];
      float4 p0 = *(const float4*)ap;
      float4 p1 = *(const float4*)(ap + 4);
      float v8[8] = {p0.x, p0.y, p0.z, p0.w, p1.x, p1.y, p1.z, p1.w};
      short8 ah, al;
      build_frags(v8, ah, al);
      acc = MFMA16(ah, BOh[ks], acc);
      acc = MFMA16(al, BOh[ks], acc);
      acc = MFMA16(ah, BOl[ks], acc);
    }
    {
      int np = n0 + c;
      int kd = np >> 5, qq = (np >> 3) & 3, half = (c >> 2) & 1, j4 = c & 3;
      #pragma unroll
      for (int r = 0; r < 4; ++r)
        hf[((kd * 2 + half) * 64 + qq * 16 + 4 * qd + r) * 4 + j4] = acc[r];
    }
    __syncthreads();   // hf ready (w2t also lands by now)
    floatx4 a2c = {0.f, 0.f, 0.f, 0.f};
    #pragma unroll
    for (int ks = 0; ks < 4; ++ks) {
      float4 p0 = *(const float4*)&hf[((ks * 2 + 0) * 64 + lane) * 4];
      float4 p1 = *(const float4*)&hf[((ks * 2 + 1) * 64 + lane) * 4];
      float v8[8] = {p0.x, p0.y, p0.z, p0.w, p1.x, p1.y, p1.z, p1.w};
      short8 ah, al;
      build_frags(v8, ah, al);
      a2c = MFMA16(ah, B1h[ks], a2c);
      a2c = MFMA16(al, B1h[ks], a2c);
      a2c = MFMA16(ah, B1l[ks], a2c);
    }
    float bj = ldx(b1, n0 + c, f);
    #pragma unroll
    for (int r = 0; r < 4; ++r) {
      float u = a2c[r] + bj;
      float inner = 0.7978845608028654f * (u + 0.044715f * u * u * u);
      xl[(4 * qd + r) * 132 + n0 + c] = 0.5f * u * (1.f + tanhf(inner));
    }
  } else {
    for (int i = t - 512; i < D * 16; i += 512) {
      int kk = i >> 4, cc = i & 15;
      w2t[cc * 132 + kk] = ldx(w2, i, f);
    }
    __syncthreads();   // matches the hf barrier in the t<512 path
  }
  __syncthreads();
  if (t < 256) {  // logits = x @ w2 + b2, float4 LDS dot
    int r = t >> 4, cc = t & 15;
    const float4* xr = (const float4*)&xl[r * 132];
    const float4* wr = (const float4*)&w2t[cc * 132];
    float s = 0.f;
    #pragma unroll
    for (int k4 = 0; k4 < D / 4; ++k4) {
      float4 xa = xr[k4], wb = wr[k4];
      s += xa.x * wb.x + xa.y * wb.y + xa.z * wb.z + xa.w * wb.w;
    }
    s += ldx(b2, cc, f);
    int idx = (row0 + r) * 16 + cc;
    if (f) ((float*)out)[idx] = s;
    else ((__hip_bfloat16*)out)[idx] = __float2bfloat16(s);
  }
}

extern "C" void kernel_launch(void* const* d_in, const int* in_sizes, int n_in,
                              void* d_out, int out_size, void* d_ws, size_t ws_size,
                              hipStream_t stream) {
  const int* eidx = (const int*)d_in[2];
  const int* src = eidx;
  const int* dst = eidx + NE;

  size_t off = 0;
  char* base = (char*)d_ws;
  auto alloc = [&](size_t nbytes) -> void* {
    void* p = base + off;
    off += (nbytes + 255) & ~(size_t)255;
    return p;
  };
  int* flag      = (int*)alloc(256);
  float* ns      = (float*)alloc(NN * sizeof(float));
  float* es      = (float*)alloc(NE * sizeof(float));
  int* deg       = (int*)alloc(NN * sizeof(int));
  int* lists     = (int*)alloc((size_t)NN * CAP * sizeof(int));
  u16* wtHi      = (u16*)alloc((size_t)7 * 16384 * sizeof(u16));
  u16* wtLo      = (u16*)alloc((size_t)7 * 16384 * sizeof(u16));
  u16* feHi      = (u16*)alloc((size_t)(NN + NE) * D * sizeof(u16));
  u16* feLo      = (u16*)alloc((size_t)(NN + NE) * D * sizeof(u16));
  float* qkv     = (float*)alloc((size_t)3 * NE * D * sizeof(float));
  float* qb = qkv, *kb = qkv + NE * D, *vb = qkv + 2 * NE * D;
  (void)qb; (void)kb; (void)vb;

  K1Args a1;
  a1.nf = d_in[0]; a1.ef = d_in[1]; a1.wrn = d_in[3]; a1.wre = d_in[4];
  a1.w[0] = d_in[5];  a1.w[1] = d_in[6];  a1.w[2] = d_in[7];
  a1.w[3] = d_in[8];  a1.w[4] = d_in[9];  a1.w[5] = d_in[10]; a1.w[6] = d_in[11];
  a1.src = src; a1.dst = dst;
  a1.ns = ns; a1.es = es; a1.deg = deg; a1.lists = lists; a1.flag = flag;
  a1.wtHi = wtHi; a1.wtLo = wtLo; a1.feHi = feHi; a1.feLo = feLo;

  // K1: scores + splits + incident lists + flag
  scores_prep_lists_kernel<<<K1_BLOCKS, 256, 0, stream>>>(a1);
  // K2: in-block top-k masks + MFMA h -> q,k,v
  h_qkv_mfma_kernel<<<NE / 16, 512, 0, stream>>>(
      ns, es, feHi, feLo, src, dst, wtHi, wtLo, qkv);
  // K3: attention + MLP (fused, ao stays in LDS)
  attn_mlp_kernel<<<NE / 16, 1024, 0, stream>>>(
      qkv, src, dst, deg, lists, wtHi, wtLo,
      d_in[12], d_in[13], d_in[14], flag, d_out);
}

// Round 4
// 150.445 us; speedup vs baseline: 1.7503x; 1.0703x over previous
//
#include <hip/hip_runtime.h>
#include <hip/hip_bf16.h>
#include <math.h>

#define NN 2048      // nodes
#define NE 4096      // edges
#define D 128
#define NODE_K 1024
#define EDGE_K 2048
#define CAP 64       // per-node incident-edge list capacity (mean degree 4)

typedef const __hip_bfloat16* bfp;
typedef unsigned short u16;
typedef __attribute__((ext_vector_type(8))) short short8;     // 8 bf16 (4 VGPRs)
typedef __attribute__((ext_vector_type(4))) float floatx4;    // MFMA acc

#define MFMA16(a, b, c) __builtin_amdgcn_mfma_f32_16x16x32_bf16(a, b, c, 0, 0, 0)

__device__ __forceinline__ float b2f(__hip_bfloat16 x) { return __bfloat162float(x); }

// dual-path loads: f=1 -> fp32 input, f=0 -> bf16 input (bf16->fp32 is exact)
__device__ __forceinline__ float ldx(const void* p, size_t i, int f) {
  return f ? ((const float*)p)[i] : b2f(((bfp)p)[i]);
}
__device__ __forceinline__ float4 ldx4(const void* p, size_t i4, int f) {
  if (f) return ((const float4*)p)[i4];
  ushort4 u = ((const ushort4*)p)[i4];
  float4 r;
  r.x = __uint_as_float(((unsigned)u.x) << 16);
  r.y = __uint_as_float(((unsigned)u.y) << 16);
  r.z = __uint_as_float(((unsigned)u.z) << 16);
  r.w = __uint_as_float(((unsigned)u.w) << 16);
  return r;
}

// RNE fp32 -> (bf16 hi, bf16 lo): x ~= hi + lo, dropped part ~2^-17 |x|
__device__ __forceinline__ void split2(float x, u16& hi, u16& lo) {
  unsigned u = __float_as_uint(x);
  unsigned h = (u + 0x7FFFu + ((u >> 16) & 1u)) >> 16;
  hi = (u16)h;
  float r = x - __uint_as_float(h << 16);
  unsigned v = __float_as_uint(r);
  lo = (u16)((v + 0x7FFFu + ((v >> 16) & 1u)) >> 16);
}
__device__ __forceinline__ void build_frags(const float* v8, short8& fh, short8& fl) {
  #pragma unroll
  for (int i = 0; i < 8; ++i) {
    u16 h, l;
    split2(v8[i], h, l);
    fh[i] = (short)h; fl[i] = (short)l;
  }
}

// per-block dtype detect from first 1024 halves of node_features (2 KB, L2-hot)
template <int NT>
__device__ __forceinline__ int detect_f(const u16* raw, int* s8) {
  int t = threadIdx.x;
  int weird = 0;
  for (int i = t; i < 1024; i += NT) {
    unsigned int bits = ((unsigned int)raw[i]) << 16;
    float x = __uint_as_float(bits);
    float ax = fabsf(x);
    if (!(ax <= 1e3f) || (x != 0.f && ax < 1e-12f)) weird++;  // nan/inf/huge/denorm
  }
  #pragma unroll
  for (int m = 32; m >= 1; m >>= 1) weird += __shfl_xor(weird, m);
  if ((t & 63) == 0) s8[t >> 6] = weird;
  __syncthreads();
  int tot = 0;
  #pragma unroll
  for (int i = 0; i < NT / 64; ++i) tot += s8[i];
  return (tot > 50) ? 1 : 0;  // 1 => inputs are fp32
}

struct K1Args {
  const void *nf, *ef, *wrn, *wre;
  const void* w[7];              // we, wn, wq, wk, wv, wo, w1 (each 128x128)
  const int *src, *dst;
  float *ns, *es;
  int *deg, *lists, *flag;
  u16 *wtHi, *wtLo;              // [7][128 n][128 k] (transposed + split)
  u16 *feHi, *feLo;              // [NN*D | NE*D] row-major feature splits
};

// ---------- K1: scores (fp64) + splits + incident lists (LDS counters) ----------
#define SCORE_BLOCKS ((NN + NE) / 4)   // 1536
#define WPREP_BLOCKS 112               // 28672 ushort4-tasks / 256
#define FSPLIT_BLOCKS 192              // 196608 float4-tasks / (256*4)
#define K1_BLOCKS (SCORE_BLOCKS + WPREP_BLOCKS + FSPLIT_BLOCKS + 1)
__global__ __launch_bounds__(256) void scores_prep_lists_kernel(K1Args a) {
  __shared__ int s8[4];
  int b = blockIdx.x, t = threadIdx.x;
  int f = detect_f<256>((const u16*)a.nf, s8);
  if (b < SCORE_BLOCKS) {
    int wid = b * 4 + (t >> 6), lane = t & 63;
    const void* base; const void* w; float* out; size_t r0;
    if (wid < NN) { base = a.nf; r0 = (size_t)wid * D; w = a.wrn; out = a.ns + wid; }
    else { int r = wid - NN; base = a.ef; r0 = (size_t)r * D; w = a.wre; out = a.es + r; }
    double p = (double)ldx(base, r0 + lane, f) * (double)ldx(w, lane, f)
             + (double)ldx(base, r0 + lane + 64, f) * (double)ldx(w, lane + 64, f);
    #pragma unroll
    for (int m = 32; m >= 1; m >>= 1) p += __shfl_xor(p, m);
    if (lane == 0) *out = (float)p;
  } else if (b < SCORE_BLOCKS + WPREP_BLOCKS) {
    // weight split+transpose, coalesced ushort4 stores: Wt[n][k0..k0+3]
    int tau = (b - SCORE_BLOCKS) * 256 + t;  // 0..28671
    int w = tau >> 12, rem = tau & 4095;
    int n = rem >> 5, k0 = (rem & 31) * 4;
    ushort4 hi, lo;
    split2(ldx(a.w[w], (size_t)(k0 + 0) * 128 + n, f), hi.x, lo.x);
    split2(ldx(a.w[w], (size_t)(k0 + 1) * 128 + n, f), hi.y, lo.y);
    split2(ldx(a.w[w], (size_t)(k0 + 2) * 128 + n, f), hi.z, lo.z);
    split2(ldx(a.w[w], (size_t)(k0 + 3) * 128 + n, f), hi.w, lo.w);
    ((ushort4*)a.wtHi)[tau] = hi;
    ((ushort4*)a.wtLo)[tau] = lo;
  } else if (b < SCORE_BLOCKS + WPREP_BLOCKS + FSPLIT_BLOCKS) {
    // feature split: float4 in, 2x ushort4 out (NF then EF, row-major)
    int fb = b - SCORE_BLOCKS - WPREP_BLOCKS;  // 0..191
    #pragma unroll
    for (int i = 0; i < 4; ++i) {
      int g4 = fb * 1024 + i * 256 + t;        // 0..196607
      float4 x = (g4 < NN * D / 4) ? ldx4(a.nf, g4, f)
                                   : ldx4(a.ef, g4 - NN * D / 4, f);
      ushort4 hi, lo;
      split2(x.x, hi.x, lo.x);
      split2(x.y, hi.y, lo.y);
      split2(x.z, hi.z, lo.z);
      split2(x.w, hi.w, lo.w);
      ((ushort4*)a.feHi)[g4] = hi;
      ((ushort4*)a.feLo)[g4] = lo;
    }
  } else {
    // incident lists via LDS degree counters (one block owns all 4096 edges)
    __shared__ int ldeg[NN];
    for (int i = t; i < NN; i += 256) ldeg[i] = 0;
    __syncthreads();
    #pragma unroll
    for (int i = 0; i < NE / 256; ++i) {
      int e = i * 256 + t;
      int sn = a.src[e], dn = a.dst[e];
      int p = atomicAdd(&ldeg[sn], 1);
      if (p < CAP) a.lists[sn * CAP + p] = e;
      if (dn != sn) {
        p = atomicAdd(&ldeg[dn], 1);
        if (p < CAP) a.lists[dn * CAP + p] = e;
      }
    }
    __syncthreads();
    for (int i = t; i < NN; i += 256) a.deg[i] = ldeg[i];
    if (t == 0) a.flag[0] = f;
  }
}

// ---------- K2: MFMA h = efm@WE + (nfs+nfd)@WN; q,k,v = h@WQ/WK/WV ----------
// 512 thr (8 waves), 16 edge rows/block; wave w owns col-tile n0 = w*16.
// Top-k masks recomputed per block (48 rank scans over L1-hot scores).
__global__ __launch_bounds__(512) void h_qkv_mfma_kernel(
    const float* __restrict__ ns, const float* __restrict__ es,
    const u16* __restrict__ feHi, const u16* __restrict__ feLo,
    const int* __restrict__ src, const int* __restrict__ dst,
    const u16* __restrict__ wtHi, const u16* __restrict__ wtLo,
    float* __restrict__ qkv) {
  __shared__ __align__(16) float hf[8 * 64 * 4];  // frag-order h (fp32), 8 KB
  __shared__ int s_msk[3][16];                    // edge_topk, nm[src], nm[dst]
  int t = threadIdx.x;
  int wave = t >> 6, lane = t & 63;
  int qd = lane >> 4, c = lane & 15;
  int row0 = blockIdx.x * 16;

  // --- in-block top-k rank scans: 48 tasks = {edge, src-node, dst-node} x 16 ---
  for (int task = wave; task < 48; task += 8) {
    int kind = task >> 4, ti = task & 15;
    int e2 = row0 + ti;
    const float* arr; int len, K, tgt;
    if (kind == 0) { arr = es; len = NE; K = EDGE_K; tgt = e2; }
    else { arr = ns; len = NN; K = NODE_K; tgt = (kind == 1) ? src[e2] : dst[e2]; }
    float si = arr[tgt];
    int rank = 0;
    for (int j4 = lane; j4 < (len >> 2); j4 += 64) {
      float4 sj = ((const float4*)arr)[j4];
      int j = j4 * 4;
      rank += (sj.x > si) || (sj.x == si && j + 0 < tgt);
      rank += (sj.y > si) || (sj.y == si && j + 1 < tgt);
      rank += (sj.z > si) || (sj.z == si && j + 2 < tgt);
      rank += (sj.w > si) || (sj.w == si && j + 3 < tgt);
    }
    #pragma unroll
    for (int m = 32; m >= 1; m >>= 1) rank += __shfl_xor(rank, m);
    if (lane == 0) s_msk[kind][ti] = (rank < K) ? 1 : 0;
  }
  __syncthreads();

  int e = row0 + c;                 // A-row this lane gathers (m = c)
  int sn = src[e], dn = dst[e];
  bool em = s_msk[0][c] && s_msk[1][c] && s_msk[2][c];
  int n0 = wave * 16;
  const u16* efH = feHi + (size_t)NN * D;
  const u16* efL = feLo + (size_t)NN * D;
  const short8 z8 = {0, 0, 0, 0, 0, 0, 0, 0};

  // prefetch ALL h-pass A-operands (24 x 16B independent loads in flight)
  short8 A1h[4], A1l[4], Sh[4], Sl[4], Dh[4], Dl[4];
  short8 BEh[4], BEl[4], BNh[4], BNl[4];
  #pragma unroll
  for (int ks = 0; ks < 4; ++ks) {
    int k0 = ks * 32 + qd * 8;
    A1h[ks] = *(const short8*)(efH + (size_t)e * D + k0);
    A1l[ks] = *(const short8*)(efL + (size_t)e * D + k0);
    Sh[ks]  = *(const short8*)(feHi + (size_t)sn * D + k0);
    Sl[ks]  = *(const short8*)(feLo + (size_t)sn * D + k0);
    Dh[ks]  = *(const short8*)(feHi + (size_t)dn * D + k0);
    Dl[ks]  = *(const short8*)(feLo + (size_t)dn * D + k0);
    size_t bo = (size_t)(n0 + c) * 128 + k0;
    BEh[ks] = *(const short8*)(wtHi + bo);
    BEl[ks] = *(const short8*)(wtLo + bo);
    BNh[ks] = *(const short8*)(wtHi + 16384 + bo);
    BNl[ks] = *(const short8*)(wtLo + 16384 + bo);
  }
  if (!em) {
    #pragma unroll
    for (int ks = 0; ks < 4; ++ks) { A1h[ks] = z8; A1l[ks] = z8; }
  }
  floatx4 accE = {0.f, 0.f, 0.f, 0.f};
  floatx4 accN = {0.f, 0.f, 0.f, 0.f};
  #pragma unroll
  for (int ks = 0; ks < 4; ++ks) {
    accE = MFMA16(A1h[ks], BEh[ks], accE);
    accN = MFMA16(Sh[ks], BNh[ks], accN);
    accE = MFMA16(A1l[ks], BEh[ks], accE);
    accN = MFMA16(Sl[ks], BNh[ks], accN);
    accE = MFMA16(A1h[ks], BEl[ks], accE);
    accN = MFMA16(Sh[ks], BNl[ks], accN);
    accN = MFMA16(Dh[ks], BNh[ks], accN);
    accN = MFMA16(Dl[ks], BNh[ks], accN);
    accN = MFMA16(Dh[ks], BNl[ks], accN);
  }
  // write h (C-layout: row=4*qd+r, col=n0+c) into frag-order LDS
  {
    int np = n0 + c;
    int kd = np >> 5, qq = (np >> 3) & 3, half = (c >> 2) & 1, j4 = c & 3;
    #pragma unroll
    for (int r = 0; r < 4; ++r)
      hf[((kd * 2 + half) * 64 + qq * 16 + 4 * qd + r) * 4 + j4] = accE[r] + accN[r];
  }
  // prefetch q/k/v B-frags while h settles
  short8 BQh[4], BQl[4], BKh[4], BKl[4], BVh[4], BVl[4];
  #pragma unroll
  for (int ks = 0; ks < 4; ++ks) {
    size_t bo = (size_t)(n0 + c) * 128 + ks * 32 + qd * 8;
    BQh[ks] = *(const short8*)(wtHi + 2 * 16384 + bo);
    BQl[ks] = *(const short8*)(wtLo + 2 * 16384 + bo);
    BKh[ks] = *(const short8*)(wtHi + 3 * 16384 + bo);
    BKl[ks] = *(const short8*)(wtLo + 3 * 16384 + bo);
    BVh[ks] = *(const short8*)(wtHi + 4 * 16384 + bo);
    BVl[ks] = *(const short8*)(wtLo + 4 * 16384 + bo);
  }
  __syncthreads();
  // q,k,v: build h-frags ONCE per ks, feed 3 accumulator chains
  floatx4 aq = {0.f, 0.f, 0.f, 0.f};
  floatx4 ak = {0.f, 0.f, 0.f, 0.f};
  floatx4 av = {0.f, 0.f, 0.f, 0.f};
  #pragma unroll
  for (int ks = 0; ks < 4; ++ks) {
    float4 p0 = *(const float4*)&hf[((ks * 2 + 0) * 64 + lane) * 4];
    float4 p1 = *(const float4*)&hf[((ks * 2 + 1) * 64 + lane) * 4];
    float v8[8] = {p0.x, p0.y, p0.z, p0.w, p1.x, p1.y, p1.z, p1.w};
    short8 ah, al;
    build_frags(v8, ah, al);
    aq = MFMA16(ah, BQh[ks], aq);
    ak = MFMA16(ah, BKh[ks], ak);
    av = MFMA16(ah, BVh[ks], av);
    aq = MFMA16(al, BQh[ks], aq);
    ak = MFMA16(al, BKh[ks], ak);
    av = MFMA16(al, BVh[ks], av);
    aq = MFMA16(ah, BQl[ks], aq);
    ak = MFMA16(ah, BKl[ks], ak);
    av = MFMA16(ah, BVl[ks], av);
  }
  #pragma unroll
  for (int r = 0; r < 4; ++r) {
    size_t ro = (size_t)(row0 + 4 * qd + r) * D + n0 + c;
    qkv[ro] = aq[r];
    qkv[(size_t)NE * D + ro] = ak[r];
    qkv[(size_t)2 * NE * D + ro] = av[r];
  }
}

// ---------- K3: batched-parallel sparse attention, block (256 thr) per edge ----------
// Phase 1: merged dedup neighbor list via ballot-compaction (all loads concurrent).
// Phase 2: score loop with NO cross-iteration dependency (pipelined gathers).
// Phase 3: two-pass softmax per head in LDS. Phase 4: weighted-V, coalesced rows.
__global__ __launch_bounds__(256) void attn_kernel(
    const float* __restrict__ qkv, const int* __restrict__ src,
    const int* __restrict__ dst, const int* __restrict__ deg,
    const int* __restrict__ lists, float* __restrict__ ao) {
  __shared__ int nb[2 * CAP];        // merged neighbor edge list
  __shared__ float sS[4][2 * CAP];   // scores -> exp weights
  __shared__ float inv_l[4];
  __shared__ int sM;
  const float* kb = qkv + (size_t)NE * D;
  const float* vb = qkv + (size_t)2 * NE * D;
  int e = blockIdx.x;
  int t = threadIdx.x;
  int wave = t >> 6, lane = t & 63;
  int sn = src[e], dn = dst[e];
  // q row for phase 2: lane owns dims 2*lane, 2*lane+1 (head = lane>>4)
  float2 qv = *(const float2*)&qkv[(size_t)e * D + 2 * lane];
  int degA = max(0, min(deg[sn], CAP));
  int degB = (dn != sn) ? max(0, min(deg[dn], CAP)) : 0;
  if (wave == 0) {
    if (lane < degA) nb[lane] = lists[sn * CAP + lane];
  } else if (wave == 1) {
    int fe = -1;
    bool keep = false;
    if (lane < degB) {
      fe = lists[dn * CAP + lane];
      keep = !(src[fe] == sn || dst[fe] == sn);  // dedup vs list A
    }
    unsigned long long mk = __ballot(keep);
    if (keep) {
      int pos = __popcll(mk & ((1ULL << lane) - 1ULL));
      nb[degA + pos] = fe;
    }
    if (lane == 0) sM = degA + __popcll(mk);
  }
  __syncthreads();
  int M = sM;
  const float scale = 0.17677669529663687f;  // 1/sqrt(32)
  // phase 2: scores (independent iterations -> loads pipeline)
  for (int i = wave; i < M; i += 4) {
    int fe = nb[i];
    float2 kk = *(const float2*)&kb[(size_t)fe * D + 2 * lane];
    float p = qv.x * kk.x + qv.y * kk.y;
    p += __shfl_xor(p, 8); p += __shfl_xor(p, 4);
    p += __shfl_xor(p, 2); p += __shfl_xor(p, 1);
    if ((lane & 15) == 0) sS[lane >> 4][i] = p * scale;
  }
  __syncthreads();
  // phase 3: per-head max + exp-sum (wave w owns head w)
  {
    float mx = -1e30f;
    for (int i = lane; i < M; i += 64) mx = fmaxf(mx, sS[wave][i]);
    #pragma unroll
    for (int mk2 = 32; mk2 >= 1; mk2 >>= 1) mx = fmaxf(mx, __shfl_xor(mx, mk2));
    float ls = 0.f;
    for (int i = lane; i < M; i += 64) {
      float w = expf(sS[wave][i] - mx);
      sS[wave][i] = w;
      ls += w;
    }
    #pragma unroll
    for (int mk2 = 32; mk2 >= 1; mk2 >>= 1) ls += __shfl_xor(ls, mk2);
    if (lane == 0) inv_l[wave] = 1.f / fmaxf(ls, 1e-37f);
  }
  __syncthreads();
  // phase 4: o[d] = sum_i w[i] * v[nb[i]][d]  (coalesced, independent loads)
  if (t < D) {
    int h = t >> 5;
    float acc0 = 0.f, acc1 = 0.f;
    int i = 0;
    for (; i + 1 < M; i += 2) {
      acc0 += sS[h][i]     * vb[(size_t)nb[i] * D + t];
      acc1 += sS[h][i + 1] * vb[(size_t)nb[i + 1] * D + t];
    }
    if (i < M) acc0 += sS[h][i] * vb[(size_t)nb[i] * D + t];
    ao[(size_t)e * D + t] = (acc0 + acc1) * inv_l[h];
  }
}

// ---------- K4: MFMA o = ao@WO; x = gelu(o@W1+b1); logits = x@W2+b2 ----------
__global__ __launch_bounds__(512) void o_mlp_mfma_kernel(
    const float* __restrict__ ao,
    const u16* __restrict__ wtHi, const u16* __restrict__ wtLo,
    const void* __restrict__ b1, const void* __restrict__ w2,
    const void* __restrict__ b2, const int* __restrict__ flag,
    void* __restrict__ out) {
  __shared__ __align__(16) float hf[8 * 64 * 4];  // frag-order o (8 KB)
  __shared__ __align__(16) float xl[16 * 132];    // gelu(x), padded
  __shared__ __align__(16) float w2t[16 * 132];   // w2 transposed [c][k], padded
  int t = threadIdx.x;
  int wave = t >> 6, lane = t & 63;
  int qd = lane >> 4, c = lane & 15;
  int f = flag[0];
  int row0 = blockIdx.x * 16;
  int n0 = wave * 16;

  // prefetch both passes' B-frags
  short8 BOh[4], BOl[4], B1h[4], B1l[4];
  #pragma unroll
  for (int ks = 0; ks < 4; ++ks) {
    size_t bo = (size_t)(n0 + c) * 128 + ks * 32 + qd * 8;
    BOh[ks] = *(const short8*)(wtHi + 5 * 16384 + bo);
    BOl[ks] = *(const short8*)(wtLo + 5 * 16384 + bo);
    B1h[ks] = *(const short8*)(wtHi + 6 * 16384 + bo);
    B1l[ks] = *(const short8*)(wtLo + 6 * 16384 + bo);
  }
  // o = ao @ WO (A gathered straight from global fp32)
  floatx4 acc = {0.f, 0.f, 0.f, 0.f};
  #pragma unroll
  for (int ks = 0; ks < 4; ++ks) {
    int k0 = ks * 32 + qd * 8;
    const float* ap = ao + (size_t)(row0 + c) * D + k0;
    float4 p0 = *(const float4*)ap;
    float4 p1 = *(const float4*)(ap + 4);
    float v8[8] = {p0.x, p0.y, p0.z, p0.w, p1.x, p1.y, p1.z, p1.w};
    short8 ah, al;
    build_frags(v8, ah, al);
    acc = MFMA16(ah, BOh[ks], acc);
    acc = MFMA16(al, BOh[ks], acc);
    acc = MFMA16(ah, BOl[ks], acc);
  }
  {
    int np = n0 + c;
    int kd = np >> 5, qq = (np >> 3) & 3, half = (c >> 2) & 1, j4 = c & 3;
    #pragma unroll
    for (int r = 0; r < 4; ++r)
      hf[((kd * 2 + half) * 64 + qq * 16 + 4 * qd + r) * 4 + j4] = acc[r];
  }
  __syncthreads();
  // x = gelu(o @ W1 + b1)
  floatx4 a2c = {0.f, 0.f, 0.f, 0.f};
  #pragma unroll
  for (int ks = 0; ks < 4; ++ks) {
    float4 p0 = *(const float4*)&hf[((ks * 2 + 0) * 64 + lane) * 4];
    float4 p1 = *(const float4*)&hf[((ks * 2 + 1) * 64 + lane) * 4];
    float v8[8] = {p0.x, p0.y, p0.z, p0.w, p1.x, p1.y, p1.z, p1.w};
    short8 ah, al;
    build_frags(v8, ah, al);
    a2c = MFMA16(ah, B1h[ks], a2c);
    a2c = MFMA16(al, B1h[ks], a2c);
    a2c = MFMA16(ah, B1l[ks], a2c);
  }
  float bj = ldx(b1, n0 + c, f);
  #pragma unroll
  for (int r = 0; r < 4; ++r) {
    float u = a2c[r] + bj;
    float inner = 0.7978845608028654f * (u + 0.044715f * u * u * u);
    xl[(4 * qd + r) * 132 + n0 + c] = 0.5f * u * (1.f + tanhf(inner));
  }
  for (int i = t; i < D * 16; i += 512) {
    int kk = i >> 4, cc = i & 15;
    w2t[cc * 132 + kk] = ldx(w2, i, f);
  }
  __syncthreads();
  if (t < 256) {  // logits = x @ w2 + b2, float4 LDS dot
    int r = t >> 4, cc = t & 15;
    const float4* xr = (const float4*)&xl[r * 132];
    const float4* wr = (const float4*)&w2t[cc * 132];
    float s = 0.f;
    #pragma unroll
    for (int k4 = 0; k4 < D / 4; ++k4) {
      float4 xa = xr[k4], wb = wr[k4];
      s += xa.x * wb.x + xa.y * wb.y + xa.z * wb.z + xa.w * wb.w;
    }
    s += ldx(b2, cc, f);
    int idx = (row0 + r) * 16 + cc;
    if (f) ((float*)out)[idx] = s;
    else ((__hip_bfloat16*)out)[idx] = __float2bfloat16(s);
  }
}

extern "C" void kernel_launch(void* const* d_in, const int* in_sizes, int n_in,
                              void* d_out, int out_size, void* d_ws, size_t ws_size,
                              hipStream_t stream) {
  const int* eidx = (const int*)d_in[2];
  const int* src = eidx;
  const int* dst = eidx + NE;

  size_t off = 0;
  char* base = (char*)d_ws;
  auto alloc = [&](size_t nbytes) -> void* {
    void* p = base + off;
    off += (nbytes + 255) & ~(size_t)255;
    return p;
  };
  int* flag      = (int*)alloc(256);
  float* ns      = (float*)alloc(NN * sizeof(float));
  float* es      = (float*)alloc(NE * sizeof(float));
  int* deg       = (int*)alloc(NN * sizeof(int));
  int* lists     = (int*)alloc((size_t)NN * CAP * sizeof(int));
  u16* wtHi      = (u16*)alloc((size_t)7 * 16384 * sizeof(u16));
  u16* wtLo      = (u16*)alloc((size_t)7 * 16384 * sizeof(u16));
  u16* feHi      = (u16*)alloc((size_t)(NN + NE) * D * sizeof(u16));
  u16* feLo      = (u16*)alloc((size_t)(NN + NE) * D * sizeof(u16));
  float* qkv     = (float*)alloc((size_t)3 * NE * D * sizeof(float));
  float* ao      = (float*)alloc((size_t)NE * D * sizeof(float));

  K1Args a1;
  a1.nf = d_in[0]; a1.ef = d_in[1]; a1.wrn = d_in[3]; a1.wre = d_in[4];
  a1.w[0] = d_in[5];  a1.w[1] = d_in[6];  a1.w[2] = d_in[7];
  a1.w[3] = d_in[8];  a1.w[4] = d_in[9];  a1.w[5] = d_in[10]; a1.w[6] = d_in[11];
  a1.src = src; a1.dst = dst;
  a1.ns = ns; a1.es = es; a1.deg = deg; a1.lists = lists; a1.flag = flag;
  a1.wtHi = wtHi; a1.wtLo = wtLo; a1.feHi = feHi; a1.feLo = feLo;

  // K1: scores + splits + incident lists + flag
  scores_prep_lists_kernel<<<K1_BLOCKS, 256, 0, stream>>>(a1);
  // K2: in-block top-k masks + MFMA h -> q,k,v
  h_qkv_mfma_kernel<<<NE / 16, 512, 0, stream>>>(
      ns, es, feHi, feLo, src, dst, wtHi, wtLo, qkv);
  // K3: batched-parallel attention (block per edge)
  attn_kernel<<<NE, 256, 0, stream>>>(qkv, src, dst, deg, lists, ao);
  // K4: MFMA o -> gelu MLP -> logits
  o_mlp_mfma_kernel<<<NE / 16, 512, 0, stream>>>(
      ao, wtHi, wtLo, d_in[12], d_in[13], d_in[14], flag, d_out);
}

// Round 5
// 139.516 us; speedup vs baseline: 1.8874x; 1.0783x over previous
//
#include <hip/hip_runtime.h>
#include <hip/hip_bf16.h>
#include <math.h>

#define NN 2048      // nodes
#define NE 4096      // edges
#define D 128
#define NODE_K 1024
#define EDGE_K 2048
#define CAP 64       // per-node incident-edge list capacity (mean degree 4)

typedef const __hip_bfloat16* bfp;
typedef unsigned short u16;
typedef __attribute__((ext_vector_type(8))) short short8;     // 8 bf16 (4 VGPRs)
typedef __attribute__((ext_vector_type(4))) float floatx4;    // MFMA acc

#define MFMA16(a, b, c) __builtin_amdgcn_mfma_f32_16x16x32_bf16(a, b, c, 0, 0, 0)

__device__ __forceinline__ float b2f(__hip_bfloat16 x) { return __bfloat162float(x); }

// dual-path loads: f=1 -> fp32 input, f=0 -> bf16 input (bf16->fp32 is exact)
__device__ __forceinline__ float ldx(const void* p, size_t i, int f) {
  return f ? ((const float*)p)[i] : b2f(((bfp)p)[i]);
}
__device__ __forceinline__ float4 ldx4(const void* p, size_t i4, int f) {
  if (f) return ((const float4*)p)[i4];
  ushort4 u = ((const ushort4*)p)[i4];
  float4 r;
  r.x = __uint_as_float(((unsigned)u.x) << 16);
  r.y = __uint_as_float(((unsigned)u.y) << 16);
  r.z = __uint_as_float(((unsigned)u.z) << 16);
  r.w = __uint_as_float(((unsigned)u.w) << 16);
  return r;
}

// RNE fp32 -> (bf16 hi, bf16 lo): x ~= hi + lo, dropped part ~2^-17 |x|
__device__ __forceinline__ void split2(float x, u16& hi, u16& lo) {
  unsigned u = __float_as_uint(x);
  unsigned h = (u + 0x7FFFu + ((u >> 16) & 1u)) >> 16;
  hi = (u16)h;
  float r = x - __uint_as_float(h << 16);
  unsigned v = __float_as_uint(r);
  lo = (u16)((v + 0x7FFFu + ((v >> 16) & 1u)) >> 16);
}
__device__ __forceinline__ void build_frags(const float* v8, short8& fh, short8& fl) {
  #pragma unroll
  for (int i = 0; i < 8; ++i) {
    u16 h, l;
    split2(v8[i], h, l);
    fh[i] = (short)h; fl[i] = (short)l;
  }
}

// per-block dtype detect from first 1024 halves of node_features (2 KB, L2-hot)
__device__ __forceinline__ int detect_f(const u16* raw, int* s4) {
  int t = threadIdx.x;
  int weird = 0;
  for (int i = t; i < 1024; i += blockDim.x) {
    unsigned int bits = ((unsigned int)raw[i]) << 16;
    float x = __uint_as_float(bits);
    float ax = fabsf(x);
    if (!(ax <= 1e3f) || (x != 0.f && ax < 1e-12f)) weird++;  // nan/inf/huge/denorm
  }
  #pragma unroll
  for (int m = 32; m >= 1; m >>= 1) weird += __shfl_xor(weird, m);
  int nw = (int)blockDim.x >> 6;
  if ((t & 63) == 0) s4[t >> 6] = weird;
  __syncthreads();
  int tot = 0;
  for (int i = 0; i < nw; ++i) tot += s4[i];
  return (tot > 50) ? 1 : 0;  // 1 => inputs are fp32
}

struct K1Args {
  const void *nf, *ef, *wrn, *wre;
  const void* w[7];              // we, wn, wq, wk, wv, wo, w1 (each 128x128)
  float *ns, *es;
  int *deg, *flag;
  u16 *wtHi, *wtLo;              // [7][128 n][128 k] (transposed + split)
  u16 *feHi, *feLo;              // [NN*D | NE*D] row-major feature splits
};

// ---------- K1: scores (fp64) + deg zero + flag + vectorized splits ----------
#define SCORE_BLOCKS ((NN + NE) / 4)   // 1536
#define WPREP_BLOCKS 112               // 28672 ushort4-tasks / 256
#define FSPLIT_BLOCKS 192              // 196608 float4-tasks / (256*4)
__global__ __launch_bounds__(256) void scores_prep_kernel(K1Args a) {
  __shared__ int s4[4];
  int b = blockIdx.x, t = threadIdx.x;
  int f = detect_f((const u16*)a.nf, s4);
  if (b < SCORE_BLOCKS) {
    int wid = b * 4 + (t >> 6), lane = t & 63;
    const void* base; const void* w; float* out; size_t r0;
    if (wid < NN) { base = a.nf; r0 = (size_t)wid * D; w = a.wrn; out = a.ns + wid; }
    else { int r = wid - NN; base = a.ef; r0 = (size_t)r * D; w = a.wre; out = a.es + r; }
    double p = (double)ldx(base, r0 + lane, f) * (double)ldx(w, lane, f)
             + (double)ldx(base, r0 + lane + 64, f) * (double)ldx(w, lane + 64, f);
    #pragma unroll
    for (int m = 32; m >= 1; m >>= 1) p += __shfl_xor(p, m);
    if (lane == 0) *out = (float)p;
  } else if (b == SCORE_BLOCKS) {
    if (t == 0) a.flag[0] = f;
    for (int i = t; i < NN; i += 256) a.deg[i] = 0;
  } else if (b <= SCORE_BLOCKS + WPREP_BLOCKS) {
    // weight split+transpose, coalesced ushort4 stores: Wt[n][k0..k0+3]
    int tau = (b - SCORE_BLOCKS - 1) * 256 + t;  // 0..28671
    int w = tau >> 12, rem = tau & 4095;
    int n = rem >> 5, k0 = (rem & 31) * 4;
    ushort4 hi, lo;
    split2(ldx(a.w[w], (size_t)(k0 + 0) * 128 + n, f), hi.x, lo.x);
    split2(ldx(a.w[w], (size_t)(k0 + 1) * 128 + n, f), hi.y, lo.y);
    split2(ldx(a.w[w], (size_t)(k0 + 2) * 128 + n, f), hi.z, lo.z);
    split2(ldx(a.w[w], (size_t)(k0 + 3) * 128 + n, f), hi.w, lo.w);
    ((ushort4*)a.wtHi)[tau] = hi;
    ((ushort4*)a.wtLo)[tau] = lo;
  } else {
    // feature split: float4 in, 2x ushort4 out (NF then EF, row-major)
    int fb = b - SCORE_BLOCKS - 1 - WPREP_BLOCKS;  // 0..191
    #pragma unroll
    for (int i = 0; i < 4; ++i) {
      int g4 = fb * 1024 + i * 256 + t;            // 0..196607
      float4 x = (g4 < NN * D / 4) ? ldx4(a.nf, g4, f)
                                   : ldx4(a.ef, g4 - NN * D / 4, f);
      ushort4 hi, lo;
      split2(x.x, hi.x, lo.x);
      split2(x.y, hi.y, lo.y);
      split2(x.z, hi.z, lo.z);
      split2(x.w, hi.w, lo.w);
      ((ushort4*)a.feHi)[g4] = hi;
      ((ushort4*)a.feLo)[g4] = lo;
    }
  }
}

// ---------- K2: node rank + edge rank + incident lists ----------
#define NMB (NN / 4)
#define EMB (NE / 4)
__global__ __launch_bounds__(256) void mask_lists_kernel(
    const float* __restrict__ ns, const float* __restrict__ es,
    const int* __restrict__ src, const int* __restrict__ dst,
    int* __restrict__ node_mask, int* __restrict__ edge_topk,
    int* __restrict__ deg, int* __restrict__ lists) {
  __shared__ __align__(16) float s[NE];
  int b = blockIdx.x, t = threadIdx.x;
  if (b < NMB) {  // exact top-k rank, stable ties (== lax.top_k)
    for (int i = t; i < NN / 4; i += 256) ((float4*)s)[i] = ((const float4*)ns)[i];
    __syncthreads();
    int i = b * 4 + (t >> 6), lane = t & 63;
    float si = s[i];
    int rank = 0;
    for (int j = lane; j < NN; j += 64) {
      float sj = s[j];
      rank += (sj > si) || (sj == si && j < i);
    }
    #pragma unroll
    for (int m = 32; m >= 1; m >>= 1) rank += __shfl_xor(rank, m);
    if (lane == 0) node_mask[i] = (rank < NODE_K) ? 1 : 0;
  } else if (b < NMB + EMB) {
    for (int i = t; i < NE / 4; i += 256) ((float4*)s)[i] = ((const float4*)es)[i];
    __syncthreads();
    int i = (b - NMB) * 4 + (t >> 6), lane = t & 63;
    float si = s[i];
    int rank = 0;
    for (int j = lane; j < NE; j += 64) {
      float sj = s[j];
      rank += (sj > si) || (sj == si && j < i);
    }
    #pragma unroll
    for (int m = 32; m >= 1; m >>= 1) rank += __shfl_xor(rank, m);
    if (lane == 0) edge_topk[i] = (rank < EDGE_K) ? 1 : 0;
  } else {
    int e = (b - NMB - EMB) * 256 + t;
    if (e < NE) {
      int sn = src[e], dn = dst[e];
      int p = atomicAdd(&deg[sn], 1);
      if (p >= 0 && p < CAP) lists[sn * CAP + p] = e;
      if (dn != sn) {
        p = atomicAdd(&deg[dn], 1);
        if (p >= 0 && p < CAP) lists[dn * CAP + p] = e;
      }
    }
  }
}

// ---------- K3: MFMA h = efm@WE + (nfs+nfd)@WN; q,k,v = h@WQ/WK/WV ----------
// 512 thr (8 waves), 16 edge rows/block; wave w owns col-tile n0 = w*16.
__global__ __launch_bounds__(512) void h_qkv_mfma_kernel(
    const u16* __restrict__ feHi, const u16* __restrict__ feLo,
    const int* __restrict__ src, const int* __restrict__ dst,
    const int* __restrict__ node_mask, const int* __restrict__ edge_topk,
    const u16* __restrict__ wtHi, const u16* __restrict__ wtLo,
    float* __restrict__ qkv) {
  __shared__ __align__(16) float hf[8 * 64 * 4];  // frag-order h (fp32), 8 KB
  int t = threadIdx.x;
  int wave = t >> 6, lane = t & 63;
  int qd = lane >> 4, c = lane & 15;
  int row0 = blockIdx.x * 16;
  int e = row0 + c;                 // A-row this lane gathers (m = c)
  int sn = src[e], dn = dst[e];
  bool em = edge_topk[e] && node_mask[sn] && node_mask[dn];
  int n0 = wave * 16;
  const u16* efH = feHi + (size_t)NN * D;
  const u16* efL = feLo + (size_t)NN * D;
  const short8 z8 = {0, 0, 0, 0, 0, 0, 0, 0};

  // prefetch ALL h-pass A-operands (24 x 16B independent loads in flight)
  short8 A1h[4], A1l[4], Sh[4], Sl[4], Dh[4], Dl[4];
  short8 BEh[4], BEl[4], BNh[4], BNl[4];
  #pragma unroll
  for (int ks = 0; ks < 4; ++ks) {
    int k0 = ks * 32 + qd * 8;
    A1h[ks] = *(const short8*)(efH + (size_t)e * D + k0);
    A1l[ks] = *(const short8*)(efL + (size_t)e * D + k0);
    Sh[ks]  = *(const short8*)(feHi + (size_t)sn * D + k0);
    Sl[ks]  = *(const short8*)(feLo + (size_t)sn * D + k0);
    Dh[ks]  = *(const short8*)(feHi + (size_t)dn * D + k0);
    Dl[ks]  = *(const short8*)(feLo + (size_t)dn * D + k0);
    size_t bo = (size_t)(n0 + c) * 128 + k0;
    BEh[ks] = *(const short8*)(wtHi + bo);
    BEl[ks] = *(const short8*)(wtLo + bo);
    BNh[ks] = *(const short8*)(wtHi + 16384 + bo);
    BNl[ks] = *(const short8*)(wtLo + 16384 + bo);
  }
  if (!em) {
    #pragma unroll
    for (int ks = 0; ks < 4; ++ks) { A1h[ks] = z8; A1l[ks] = z8; }
  }
  floatx4 accE = {0.f, 0.f, 0.f, 0.f};
  floatx4 accN = {0.f, 0.f, 0.f, 0.f};
  #pragma unroll
  for (int ks = 0; ks < 4; ++ks) {
    accE = MFMA16(A1h[ks], BEh[ks], accE);
    accN = MFMA16(Sh[ks], BNh[ks], accN);
    accE = MFMA16(A1l[ks], BEh[ks], accE);
    accN = MFMA16(Sl[ks], BNh[ks], accN);
    accE = MFMA16(A1h[ks], BEl[ks], accE);
    accN = MFMA16(Sh[ks], BNl[ks], accN);
    accN = MFMA16(Dh[ks], BNh[ks], accN);
    accN = MFMA16(Dl[ks], BNh[ks], accN);
    accN = MFMA16(Dh[ks], BNl[ks], accN);
  }
  // write h (C-layout: row=4*qd+r, col=n0+c) into frag-order LDS
  {
    int np = n0 + c;
    int kd = np >> 5, qq = (np >> 3) & 3, half = (c >> 2) & 1, j4 = c & 3;
    #pragma unroll
    for (int r = 0; r < 4; ++r)
      hf[((kd * 2 + half) * 64 + qq * 16 + 4 * qd + r) * 4 + j4] = accE[r] + accN[r];
  }
  // prefetch q/k/v B-frags while h settles
  short8 BQh[4], BQl[4], BKh[4], BKl[4], BVh[4], BVl[4];
  #pragma unroll
  for (int ks = 0; ks < 4; ++ks) {
    size_t bo = (size_t)(n0 + c) * 128 + ks * 32 + qd * 8;
    BQh[ks] = *(const short8*)(wtHi + 2 * 16384 + bo);
    BQl[ks] = *(const short8*)(wtLo + 2 * 16384 + bo);
    BKh[ks] = *(const short8*)(wtHi + 3 * 16384 + bo);
    BKl[ks] = *(const short8*)(wtLo + 3 * 16384 + bo);
    BVh[ks] = *(const short8*)(wtHi + 4 * 16384 + bo);
    BVl[ks] = *(const short8*)(wtLo + 4 * 16384 + bo);
  }
  __syncthreads();
  // q,k,v: build h-frags ONCE per ks, feed 3 accumulator chains
  floatx4 aq = {0.f, 0.f, 0.f, 0.f};
  floatx4 ak = {0.f, 0.f, 0.f, 0.f};
  floatx4 av = {0.f, 0.f, 0.f, 0.f};
  #pragma unroll
  for (int ks = 0; ks < 4; ++ks) {
    float4 p0 = *(const float4*)&hf[((ks * 2 + 0) * 64 + lane) * 4];
    float4 p1 = *(const float4*)&hf[((ks * 2 + 1) * 64 + lane) * 4];
    float v8[8] = {p0.x, p0.y, p0.z, p0.w, p1.x, p1.y, p1.z, p1.w};
    short8 ah, al;
    build_frags(v8, ah, al);
    aq = MFMA16(ah, BQh[ks], aq);
    ak = MFMA16(ah, BKh[ks], ak);
    av = MFMA16(ah, BVh[ks], av);
    aq = MFMA16(al, BQh[ks], aq);
    ak = MFMA16(al, BKh[ks], ak);
    av = MFMA16(al, BVh[ks], av);
    aq = MFMA16(ah, BQl[ks], aq);
    ak = MFMA16(ah, BKl[ks], ak);
    av = MFMA16(ah, BVl[ks], av);
  }
  #pragma unroll
  for (int r = 0; r < 4; ++r) {
    size_t ro = (size_t)(row0 + 4 * qd + r) * D + n0 + c;
    qkv[ro] = aq[r];
    qkv[(size_t)NE * D + ro] = ak[r];
    qkv[(size_t)2 * NE * D + ro] = av[r];
  }
}

// ---------- K4: sparse edge attention, one block (128 thr) per query edge --------
// Dual independent online-softmax chains (list A and list B processed in the
// SAME loop iteration) -> 2x ILP on the serial dependent chain; exact merge at
// the end (same math as the verified R1 partition merge). No LDS, no barriers.
__global__ void attn_kernel(const float* __restrict__ q, const float* __restrict__ k,
                            const float* __restrict__ v, const int* __restrict__ src,
                            const int* __restrict__ dst, const int* __restrict__ deg,
                            const int* __restrict__ lists, float* __restrict__ ao) {
  int e = blockIdx.x;
  int j = threadIdx.x;  // head = j/32, d = j%32 (shfl_xor<32 stays in-head)
  float qj = q[(size_t)e * D + j];
  int sn = src[e], dn = dst[e];
  const float scale = 0.17677669529663687f;  // 1/sqrt(32)
  int degA = max(0, min(deg[sn], CAP));
  int degB = (dn != sn) ? max(0, min(deg[dn], CAP)) : 0;
  float mA = -1e30f, lA = 0.f, aA = 0.f;
  float mB = -1e30f, lB = 0.f, aB = 0.f;
  int n = max(degA, degB);
  for (int i = 0; i < n; ++i) {
    bool doA = (i < degA);           // block-uniform guards: no divergence
    bool doB = (i < degB);
    int feA = doA ? lists[sn * CAP + i] : 0;
    int feB = doB ? lists[dn * CAP + i] : 0;
    if (doB) doB = !(src[feB] == sn || dst[feB] == sn);  // dedup vs list A
    float pA = 0.f, pB = 0.f, vA = 0.f, vB = 0.f;
    if (doA) { pA = qj * k[(size_t)feA * D + j]; vA = v[(size_t)feA * D + j]; }
    if (doB) { pB = qj * k[(size_t)feB * D + j]; vB = v[(size_t)feB * D + j]; }
    #pragma unroll
    for (int mk = 16; mk >= 1; mk >>= 1) {
      pA += __shfl_xor(pA, mk);
      pB += __shfl_xor(pB, mk);
    }
    if (doA) {
      float s = pA * scale;
      float mn = fmaxf(mA, s);
      float corr = expf(mA - mn);
      float w = expf(s - mn);
      lA = lA * corr + w;
      aA = aA * corr + w * vA;
      mA = mn;
    }
    if (doB) {
      float s = pB * scale;
      float mn = fmaxf(mB, s);
      float corr = expf(mB - mn);
      float w = expf(s - mn);
      lB = lB * corr + w;
      aB = aB * corr + w * vB;
      mB = mn;
    }
  }
  // exact merge of the two partial softmaxes (cB -> 0 when list B empty)
  float M = fmaxf(mA, mB);
  float cA = expf(mA - M), cB = expf(mB - M);
  float l = lA * cA + lB * cB;
  float acc = aA * cA + aB * cB;
  ao[(size_t)e * D + j] = acc / fmaxf(l, 1e-37f);
}

// ---------- K5: MFMA o = ao@WO; x = gelu(o@W1+b1); logits = x@W2+b2 ----------
__global__ __launch_bounds__(512) void o_mlp_mfma_kernel(
    const float* __restrict__ ao,
    const u16* __restrict__ wtHi, const u16* __restrict__ wtLo,
    const void* __restrict__ b1, const void* __restrict__ w2,
    const void* __restrict__ b2, const int* __restrict__ flag,
    void* __restrict__ out) {
  __shared__ __align__(16) float hf[8 * 64 * 4];  // frag-order o (8 KB)
  __shared__ __align__(16) float xl[16 * 132];    // x row-major, padded
  __shared__ __align__(16) float w2t[16 * 132];   // w2 transposed [c][k], padded
  int t = threadIdx.x;
  int wave = t >> 6, lane = t & 63;
  int qd = lane >> 4, c = lane & 15;
  int f = flag[0];
  int row0 = blockIdx.x * 16;
  int n0 = wave * 16;

  // prefetch both passes' B-frags
  short8 BOh[4], BOl[4], B1h[4], B1l[4];
  #pragma unroll
  for (int ks = 0; ks < 4; ++ks) {
    size_t bo = (size_t)(n0 + c) * 128 + ks * 32 + qd * 8;
    BOh[ks] = *(const short8*)(wtHi + 5 * 16384 + bo);
    BOl[ks] = *(const short8*)(wtLo + 5 * 16384 + bo);
    B1h[ks] = *(const short8*)(wtHi + 6 * 16384 + bo);
    B1l[ks] = *(const short8*)(wtLo + 6 * 16384 + bo);
  }
  // o = ao @ WO (A gathered straight from global fp32)
  floatx4 acc = {0.f, 0.f, 0.f, 0.f};
  #pragma unroll
  for (int ks = 0; ks < 4; ++ks) {
    int k0 = ks * 32 + qd * 8;
    const float* ap = ao + (size_t)(row0 + c) * D + k0;
    float4 p0 = *(const float4*)ap;
    float4 p1 = *(const float4*)(ap + 4);
    float v8[8] = {p0.x, p0.y, p0.z, p0.w, p1.x, p1.y, p1.z, p1.w};
    short8 ah, al;
    build_frags(v8, ah, al);
    acc = MFMA16(ah, BOh[ks], acc);
    acc = MFMA16(al, BOh[ks], acc);
    acc = MFMA16(ah, BOl[ks], acc);
  }
  {
    int np = n0 + c;
    int kd = np >> 5, qq = (np >> 3) & 3, half = (c >> 2) & 1, j4 = c & 3;
    #pragma unroll
    for (int r = 0; r < 4; ++r)
      hf[((kd * 2 + half) * 64 + qq * 16 + 4 * qd + r) * 4 + j4] = acc[r];
  }
  __syncthreads();
  // x = gelu(o @ W1 + b1)
  floatx4 a2c = {0.f, 0.f, 0.f, 0.f};
  #pragma unroll
  for (int ks = 0; ks < 4; ++ks) {
    float4 p0 = *(const float4*)&hf[((ks * 2 + 0) * 64 + lane) * 4];
    float4 p1 = *(const float4*)&hf[((ks * 2 + 1) * 64 + lane) * 4];
    float v8[8] = {p0.x, p0.y, p0.z, p0.w, p1.x, p1.y, p1.z, p1.w};
    short8 ah, al;
    build_frags(v8, ah, al);
    a2c = MFMA16(ah, B1h[ks], a2c);
    a2c = MFMA16(al, B1h[ks], a2c);
    a2c = MFMA16(ah, B1l[ks], a2c);
  }
  float bj = ldx(b1, n0 + c, f);
  #pragma unroll
  for (int r = 0; r < 4; ++r) {
    float u = a2c[r] + bj;
    float inner = 0.7978845608028654f * (u + 0.044715f * u * u * u);
    xl[(4 * qd + r) * 132 + n0 + c] = 0.5f * u * (1.f + tanhf(inner));
  }
  for (int i = t; i < D * 16; i += 512) {
    int kk = i >> 4, cc = i & 15;
    w2t[cc * 132 + kk] = ldx(w2, i, f);
  }
  __syncthreads();
  if (t < 256) {  // logits = x @ w2 + b2, float4 LDS dot (rows 16B-aligned)
    int r = t >> 4, cc = t & 15;
    const float4* xr = (const float4*)&xl[r * 132];
    const float4* wr = (const float4*)&w2t[cc * 132];
    float s = 0.f;
    #pragma unroll
    for (int k4 = 0; k4 < D / 4; ++k4) {
      float4 xa = xr[k4], wb = wr[k4];
      s += xa.x * wb.x + xa.y * wb.y + xa.z * wb.z + xa.w * wb.w;
    }
    s += ldx(b2, cc, f);
    int idx = (row0 + r) * 16 + cc;
    if (f) ((float*)out)[idx] = s;
    else ((__hip_bfloat16*)out)[idx] = __float2bfloat16(s);
  }
}

extern "C" void kernel_launch(void* const* d_in, const int* in_sizes, int n_in,
                              void* d_out, int out_size, void* d_ws, size_t ws_size,
                              hipStream_t stream) {
  const int* eidx = (const int*)d_in[2];
  const int* src = eidx;
  const int* dst = eidx + NE;

  size_t off = 0;
  char* base = (char*)d_ws;
  auto alloc = [&](size_t nbytes) -> void* {
    void* p = base + off;
    off += (nbytes + 255) & ~(size_t)255;
    return p;
  };
  int* flag      = (int*)alloc(256);
  float* ns      = (float*)alloc(NN * sizeof(float));
  float* es      = (float*)alloc(NE * sizeof(float));
  int* node_mask = (int*)alloc(NN * sizeof(int));
  int* edge_topk = (int*)alloc(NE * sizeof(int));
  int* deg       = (int*)alloc(NN * sizeof(int));
  int* lists     = (int*)alloc((size_t)NN * CAP * sizeof(int));
  u16* wtHi      = (u16*)alloc((size_t)7 * 16384 * sizeof(u16));
  u16* wtLo      = (u16*)alloc((size_t)7 * 16384 * sizeof(u16));
  u16* feHi      = (u16*)alloc((size_t)(NN + NE) * D * sizeof(u16));
  u16* feLo      = (u16*)alloc((size_t)(NN + NE) * D * sizeof(u16));
  float* qkv     = (float*)alloc((size_t)3 * NE * D * sizeof(float));
  float* ao      = (float*)alloc((size_t)NE * D * sizeof(float));
  float* qb = qkv, *kb = qkv + NE * D, *vb = qkv + 2 * NE * D;

  K1Args a1;
  a1.nf = d_in[0]; a1.ef = d_in[1]; a1.wrn = d_in[3]; a1.wre = d_in[4];
  a1.w[0] = d_in[5];  a1.w[1] = d_in[6];  a1.w[2] = d_in[7];
  a1.w[3] = d_in[8];  a1.w[4] = d_in[9];  a1.w[5] = d_in[10]; a1.w[6] = d_in[11];
  a1.ns = ns; a1.es = es; a1.deg = deg; a1.flag = flag;
  a1.wtHi = wtHi; a1.wtLo = wtLo; a1.feHi = feHi; a1.feLo = feLo;

  // K1: scores + flag + deg zero + vectorized weight/feature splits
  scores_prep_kernel<<<SCORE_BLOCKS + 1 + WPREP_BLOCKS + FSPLIT_BLOCKS, 256, 0,
                       stream>>>(a1);
  // K2: top-k ranks + incident lists
  mask_lists_kernel<<<NMB + EMB + NE / 256, 256, 0, stream>>>(
      ns, es, src, dst, node_mask, edge_topk, deg, lists);
  // K3: MFMA h -> q,k,v
  h_qkv_mfma_kernel<<<NE / 16, 512, 0, stream>>>(
      feHi, feLo, src, dst, node_mask, edge_topk, wtHi, wtLo, qkv);
  // K4: sparse attention (dual-chain ILP)
  attn_kernel<<<NE, 128, 0, stream>>>(qb, kb, vb, src, dst, deg, lists, ao);
  // K5: MFMA o -> gelu MLP -> logits
  o_mlp_mfma_kernel<<<NE / 16, 512, 0, stream>>>(
      ao, wtHi, wtLo, d_in[12], d_in[13], d_in[14], flag, d_out);
}